// Round 11
// baseline (1227.420 us; speedup 1.0000x reference)
//
#include <hip/hip_runtime.h>
#include <stdint.h>
#include <stddef.h>

constexpr int IMH = 192;
constexpr int IMW = 192;
constexpr int HW  = 36864;   // 192*192
constexpr int BB  = 2;
constexpr int CC  = 64;
constexpr int CHF = 32;      // half channels (sorted part)
constexpr int C5  = 320;     // 5*CC
constexpr int NQ  = 9216;    // HW/4
constexpr int CROWS = 64;    // fuse-pipeline chunk rows
constexpr int CHWN  = CROWS * IMW;  // 12288 cols per chunk
constexpr int NCHUNK = 32;   // attn_qk n-chunks per z
constexpr int CHN = HW / 4 / NCHUNK;  // 288 n per chunk
constexpr int NSEG = 12;     // radix segments per row (cntG fits the free hole exactly)
constexpr int SEGN = HW / NSEG;      // 3072 elements per segment (= 12 * 256)
constexpr int NBIN = 2048;   // 11-bit radix

typedef float fx2 __attribute__((ext_vector_type(2)));
typedef float fx4 __attribute__((ext_vector_type(4)));
typedef _Float16 f16;
typedef _Float16 f16x8 __attribute__((ext_vector_type(8)));
typedef float f32x4 __attribute__((ext_vector_type(4)));

// ---------- float <-> monotone uint32 (order-preserving, invertible) ----------
static __device__ __forceinline__ uint32_t f2s(float f) {
    uint32_t u = __float_as_uint(f);
    return (u & 0x80000000u) ? ~u : (u | 0x80000000u);
}
static __device__ __forceinline__ float s2f(uint32_t s) {
    uint32_t u = (s & 0x80000000u) ? (s & 0x7FFFFFFFu) : ~s;
    return __uint_as_float(u);
}

// ---------- multi-column bitonic: 256 slots x 16 lanes-wide in LDS, 256 threads ----------
static __device__ __forceinline__ void bitonic256x16(uint64_t (*keys)[17], int tid) {
    int wl = tid & 15;
    int p0 = tid >> 4;
    for (unsigned k = 2; k <= 256; k <<= 1) {
        for (unsigned j = k >> 1; j; j >>= 1) {
            __syncthreads();
            #pragma unroll
            for (int it = 0; it < 8; ++it) {
                unsigned pp = (unsigned)(p0 + it * 16);
                unsigned i = ((pp & ~(j - 1)) << 1) | (pp & (j - 1));
                unsigned q = i | j;
                bool up = ((i & k) == 0);
                uint64_t a = keys[i][wl], b = keys[q][wl];
                if ((a > b) == up) { keys[i][wl] = b; keys[q][wl] = a; }
            }
        }
    }
    __syncthreads();
}

// ---------- K1: stable sort along H, tiled: 16 adjacent w-columns per block ----------
__global__ __launch_bounds__(256) void k_sort_h(const float* __restrict__ x, float* __restrict__ A,
                                                int* __restrict__ idx_h) {
    __shared__ uint64_t keys[256][17];
    int tid = threadIdx.x;
    int blk = blockIdx.x;                 // b*CHF*12 + c*12 + wt
    int wt = blk % 12;
    int c  = (blk / 12) % CHF;
    int b  = blk / (12 * CHF);
    int w0 = wt * 16;
    const float* base = x + ((size_t)(b * CC) + c) * HW + w0;
    #pragma unroll
    for (int l = 0; l < 12; ++l) {
        int idx = l * 256 + tid;          // 0..3071
        int h = idx >> 4, wl = idx & 15;
        keys[h][wl] = (((uint64_t)f2s(base[(size_t)h * IMW + wl])) << 32) | (uint32_t)h;
    }
    #pragma unroll
    for (int l = 0; l < 4; ++l) {         // pad slots 192..255
        int idx = l * 256 + tid;
        keys[192 + (idx >> 4)][idx & 15] = ~0ull;
    }
    bitonic256x16(keys, tid);
    float* ocol = A + ((size_t)(b * CC) + c) * HW + w0;
    int* icol = idx_h + ((size_t)(b * CHF) + c) * HW + w0;
    #pragma unroll
    for (int l = 0; l < 12; ++l) {
        int idx = l * 256 + tid;
        int h = idx >> 4, wl = idx & 15;
        uint64_t kk = keys[h][wl];
        ocol[(size_t)h * IMW + wl] = s2f((uint32_t)(kk >> 32));
        icol[(size_t)h * IMW + wl] = (int)(kk & 0xFFFFFFFFull);
    }
}

// ---------- K2: stable sort along W, tiled: 16 rows per block, in-place on A ----------
__global__ __launch_bounds__(256) void k_sort_w(float* __restrict__ A, int* __restrict__ idx_w) {
    __shared__ uint64_t keys[256][17];
    int tid = threadIdx.x;
    int blk = blockIdx.x;                 // b*CHF*12 + c*12 + ht
    int ht = blk % 12;
    int c  = (blk / 12) % CHF;
    int b  = blk / (12 * CHF);
    int h0 = ht * 16;
    float* base = A + ((size_t)(b * CC) + c) * HW + (size_t)h0 * IMW;
    #pragma unroll
    for (int l = 0; l < 12; ++l) {
        int idx = l * 256 + tid;          // 0..3071
        int hl = idx / 192, w = idx % 192;
        keys[w][hl] = (((uint64_t)f2s(base[(size_t)hl * IMW + w])) << 32) | (uint32_t)w;
    }
    #pragma unroll
    for (int l = 0; l < 4; ++l) {         // pad slots 192..255
        int idx = l * 256 + tid;
        keys[192 + (idx >> 4)][idx & 15] = ~0ull;
    }
    bitonic256x16(keys, tid);
    int* irow = idx_w + ((size_t)(b * CHF) + c) * HW + (size_t)h0 * IMW;
    #pragma unroll
    for (int l = 0; l < 12; ++l) {
        int idx = l * 256 + tid;
        int hl = idx / 192, w = idx % 192;
        uint64_t kk = keys[w][hl];
        base[(size_t)hl * IMW + w] = s2f((uint32_t)(kk >> 32));
        irow[(size_t)hl * IMW + w] = (int)(kk & 0xFFFFFFFFull);
    }
}

// ---------- K3: q = W_qkv(320x64) * A(64xHW) per batch ----------
__global__ __launch_bounds__(256) void k_gemm_q(const float* __restrict__ wq, const float* __restrict__ A,
                                                const float* __restrict__ x, float* __restrict__ q) {
    __shared__ float Wt[64][68];
    __shared__ float Xt[64][68];
    int tid = threadIdx.x;
    int n0 = blockIdx.x * 64, m0 = blockIdx.y * 64, b = blockIdx.z;
    for (int l = 0; l < 16; ++l) {
        int idx = l * 256 + tid;
        int cc = idx & 63, m = idx >> 6;
        Wt[cc][m] = wq[(size_t)(m0 + m) * 64 + cc];
    }
    for (int l = 0; l < 16; ++l) {
        int idx = l * 256 + tid;
        int n = idx & 63, cc = idx >> 6;
        const float* sp = (cc < CHF) ? A : x;
        Xt[cc][n] = sp[((size_t)(b * CC) + cc) * HW + n0 + n];
    }
    __syncthreads();
    int ty = tid >> 4, tx = tid & 15;
    float acc[4][4] = {};
    for (int cc = 0; cc < 64; ++cc) {
        float4 av = *(const float4*)&Wt[cc][ty * 4];
        float4 bv = *(const float4*)&Xt[cc][tx * 4];
        float aa[4] = {av.x, av.y, av.z, av.w};
        float bb[4] = {bv.x, bv.y, bv.z, bv.w};
        #pragma unroll
        for (int i = 0; i < 4; ++i)
            #pragma unroll
            for (int j = 0; j < 4; ++j)
                acc[i][j] = fmaf(aa[i], bb[j], acc[i][j]);
    }
    for (int i = 0; i < 4; ++i) {
        float4 o;
        o.x = acc[i][0]; o.y = acc[i][1]; o.z = acc[i][2]; o.w = acc[i][3];
        *(float4*)&q[((size_t)(b * C5) + m0 + ty * 4 + i) * HW + n0 + tx * 4] = o;
    }
}

// ---------- K4: depthwise conv KSxKS (zero pad) for a 64-row chunk starting at r0 ----------
template <int KS>
__global__ __launch_bounds__(256) void k_dwconv(const float* __restrict__ q, const float* __restrict__ wd,
                                                float* __restrict__ slice, int r0) {
    constexpr int PAD = KS / 2;
    constexpr int EXT = 32 + 2 * PAD;
    __shared__ float tile[EXT][EXT];
    int tid = threadIdx.x;
    int b = blockIdx.z, c = blockIdx.y;
    int t = blockIdx.x;                  // 12 tiles: 2 tile-rows x 6 tile-cols
    int ty0 = r0 + (t / 6) * 32, tx0 = (t % 6) * 32;
    const float* src = q + ((size_t)(b * C5) + c) * HW;
    for (int i = tid; i < EXT * EXT; i += 256) {
        int iy = i / EXT, ix = i % EXT;
        int gy = ty0 + iy - PAD, gx = tx0 + ix - PAD;
        float v = 0.f;
        if (gy >= 0 && gy < IMH && gx >= 0 && gx < IMW) v = src[gy * IMW + gx];
        tile[iy][ix] = v;
    }
    __syncthreads();
    float wreg[KS * KS];
    #pragma unroll
    for (int i = 0; i < KS * KS; ++i) wreg[i] = wd[(size_t)c * KS * KS + i];
    float* dst = slice + ((size_t)(b * C5) + c) * CHWN;
    #pragma unroll
    for (int k = 0; k < 4; ++k) {
        int pix = k * 256 + tid;
        int py = pix >> 5, px = pix & 31;
        float acc = 0.f;
        #pragma unroll
        for (int ky = 0; ky < KS; ++ky)
            #pragma unroll
            for (int kx = 0; kx < KS; ++kx)
                acc = fmaf(tile[py + ky][px + kx], wreg[ky * KS + kx], acc);
        dst[(ty0 - r0 + py) * IMW + tx0 + px] = acc;
    }
}

// ---------- K5: qkv(chunk) (+)= W_fuse[:, g*320:(g+1)*320] * slice(chunk) ----------
// v6: MFMA f16x2 + INTERLEAVED output layout for q1/k1/q2/k2 (quad per (c,j));
// v-plane contiguous in qkvV for the radix sort.
__global__ __launch_bounds__(256) void k_gemm_fuse(const float* __restrict__ wf,
                                                   const float* __restrict__ slice, const float* __restrict__ bias,
                                                   float* __restrict__ qkvI, float* __restrict__ qkvV,
                                                   int g, int r0) {
    __shared__ f16 Ah[64][40];
    __shared__ f16 Al[64][40];
    int tid = threadIdx.x;
    int n0 = blockIdx.x * 128, py = blockIdx.y, m0 = py * 64, b = blockIdx.z;
    int lane = tid & 63, wv = tid >> 6;
    int l15 = lane & 15, lg = lane >> 4;
    int nwave = n0 + wv * 32;                 // wave's 32-col n-strip
    int sm = tid >> 2, skr = (tid & 3) * 8;   // W staging: m=tid>>2, 8 consecutive k
    int gk = g * 320;
    f32x4 acc[4][2];
    #pragma unroll
    for (int i = 0; i < 4; ++i)
        #pragma unroll
        for (int j = 0; j < 2; ++j)
            acc[i][j] = (f32x4){0.f, 0.f, 0.f, 0.f};

    const float* xcol = slice + (size_t)(b * C5) * CHWN + nwave + l15;
    const float* wrow = wf + (size_t)(m0 + sm) * 960 + gk + skr;

    for (int k0 = 0; k0 < 320; k0 += 32) {
        if (k0) __syncthreads();
        // stage W tile: fp32 -> f16 hi/lo split in registers -> LDS
        {
            float4 w0 = *(const float4*)(wrow + k0);
            float4 w1 = *(const float4*)(wrow + k0 + 4);
            float wvv[8] = {w0.x, w0.y, w0.z, w0.w, w1.x, w1.y, w1.z, w1.w};
            f16x8 hv, lv;
            #pragma unroll
            for (int j = 0; j < 8; ++j) {
                f16 h = (f16)wvv[j];
                hv[j] = h;
                lv[j] = (f16)(wvv[j] - (float)h);
            }
            *(f16x8*)&Ah[sm][skr] = hv;
            *(f16x8*)&Al[sm][skr] = lv;
        }
        float xv[2][8];
        #pragma unroll
        for (int fn = 0; fn < 2; ++fn)
            #pragma unroll
            for (int j = 0; j < 8; ++j)
                xv[fn][j] = xcol[(size_t)(k0 + lg * 8 + j) * CHWN + fn * 16];
        __syncthreads();
        f16x8 bh[2], bl[2];
        #pragma unroll
        for (int fn = 0; fn < 2; ++fn)
            #pragma unroll
            for (int j = 0; j < 8; ++j) {
                float v = xv[fn][j];
                f16 h = (f16)v;
                bh[fn][j] = h;
                bl[fn][j] = (f16)(v - (float)h);
            }
        #pragma unroll
        for (int fm = 0; fm < 4; ++fm) {
            f16x8 ah = *(const f16x8*)&Ah[fm * 16 + l15][lg * 8];
            f16x8 al = *(const f16x8*)&Al[fm * 16 + l15][lg * 8];
            #pragma unroll
            for (int fn = 0; fn < 2; ++fn) {
                acc[fm][fn] = __builtin_amdgcn_mfma_f32_16x16x32_f16(ah, bh[fn], acc[fm][fn], 0, 0, 0);
                acc[fm][fn] = __builtin_amdgcn_mfma_f32_16x16x32_f16(ah, bl[fn], acc[fm][fn], 0, 0, 0);
                acc[fm][fn] = __builtin_amdgcn_mfma_f32_16x16x32_f16(al, bh[fn], acc[fm][fn], 0, 0, 0);
            }
        }
    }

    #pragma unroll
    for (int fm = 0; fm < 4; ++fm) {
        #pragma unroll
        for (int r = 0; r < 4; ++r) {
            int m = m0 + fm * 16 + lg * 4 + r;
            int cg = m & 63;
            size_t colb = (size_t)r0 * IMW + nwave + l15;
            if (py < 4) {
                float* bp = qkvI + ((size_t)(b * CC + cg) * HW) * 4 + py;
                if (g == 0) {
                    float bv = bias[m];
                    #pragma unroll
                    for (int fn = 0; fn < 2; ++fn)
                        bp[(colb + fn * 16) * 4] = acc[fm][fn][r] + bv;
                } else {
                    #pragma unroll
                    for (int fn = 0; fn < 2; ++fn)
                        bp[(colb + fn * 16) * 4] += acc[fm][fn][r];
                }
            } else {
                float* bp = qkvV + (size_t)(b * CC + cg) * HW;
                if (g == 0) {
                    float bv = bias[m];
                    #pragma unroll
                    for (int fn = 0; fn < 2; ++fn)
                        bp[colb + fn * 16] = acc[fm][fn][r] + bv;
                } else {
                    #pragma unroll
                    for (int fn = 0; fn < 2; ++fn)
                        bp[colb + fn * 16] += acc[fm][fn][r];
                }
            }
        }
    }
}

// ---------- K6b-1: per-(row,seg) 11-bit digit histogram ----------
// FIRST=1: read qkvV v-plane directly (key formed on the fly, shift==32).
template <int FIRST>
__global__ __launch_bounds__(256) void k_rcount(const uint64_t* __restrict__ in, const float* __restrict__ qkvv,
                                                uint32_t* __restrict__ cntG, int shift) {
    __shared__ uint32_t hist[NBIN];
    int t = threadIdx.x;
    int seg = blockIdx.x, row = blockIdx.y;
    #pragma unroll
    for (int k = 0; k < NBIN / 256; ++k) hist[k * 256 + t] = 0;
    __syncthreads();
    if (FIRST) {
        const float* srcf = qkvv + (size_t)row * HW + (size_t)seg * SEGN;
        #pragma unroll
        for (int i = 0; i < SEGN / 256; ++i) {
            unsigned d = f2s(srcf[i * 256 + t]) & (NBIN - 1);   // shift==32
            atomicAdd(&hist[d], 1u);
        }
    } else {
        const uint64_t* src = in + (size_t)row * HW + (size_t)seg * SEGN;
        #pragma unroll
        for (int i = 0; i < SEGN / 256; ++i) {
            unsigned d = (unsigned)(src[i * 256 + t] >> shift) & (NBIN - 1);
            atomicAdd(&hist[d], 1u);
        }
    }
    __syncthreads();
    uint32_t* dstc = cntG + ((size_t)row * NSEG + seg) * NBIN;
    #pragma unroll
    for (int k = 0; k < NBIN / 256; ++k) dstc[k * 256 + t] = hist[k * 256 + t];
}

// ---------- K6b-2: per-row two-level scan -> absolute dest base per (seg,digit) ----------
__global__ __launch_bounds__(256) void k_rscan(uint32_t* __restrict__ cntG) {
    __shared__ uint32_t tot[NBIN];
    __shared__ uint32_t gsum[256];
    __shared__ uint32_t gbase[256];
    int t = threadIdx.x;
    int row = blockIdx.x;
    uint32_t* base = cntG + (size_t)row * NSEG * NBIN;
    uint32_t loc = 0;
    #pragma unroll
    for (int k = 0; k < NBIN / 256; ++k) {
        int bn = t * (NBIN / 256) + k;
        uint32_t s = 0;
        for (int sg = 0; sg < NSEG; ++sg) s += base[sg * NBIN + bn];
        tot[bn] = s;
        loc += s;
    }
    gsum[t] = loc;
    __syncthreads();
    if (t == 0) {
        uint32_t acc = 0;
        for (int i = 0; i < 256; ++i) { uint32_t v = gsum[i]; gbase[i] = acc; acc += v; }
    }
    __syncthreads();
    uint32_t run = gbase[t];
    #pragma unroll
    for (int k = 0; k < NBIN / 256; ++k) {
        int bn = t * (NBIN / 256) + k;
        uint32_t tv = tot[bn];
        uint32_t r2 = run;
        for (int sg = 0; sg < NSEG; ++sg) {
            uint32_t cv = base[sg * NBIN + bn];
            base[sg * NBIN + bn] = r2;
            r2 += cv;
        }
        run += tv;
    }
}

// ---------- K6b-3: stable scatter (11-bit): ballot rank + cross-wave prefix + running base ----------
// v2: XCD-swizzled 1D grid (1536) — all 12 segment-blocks of a row share one XCD so
// their random 8B writes into the same 288KB destination row merge in ONE L2 instead
// of being duplicated (partially dirty) across 12 XCD L2s. (Round-10 counters: 144MB
// written vs 75.5MB ideal = cross-XCD line duplication.)
// MODE 0: key->key. MODE 1: qkvV->key. MODE 2: key->vs+idxv (unpack fused).
template <int MODE>
__global__ __launch_bounds__(256) void k_rscatter(const uint64_t* __restrict__ in, const float* __restrict__ qkvv,
                                                  uint64_t* __restrict__ out, float* __restrict__ vso,
                                                  int* __restrict__ idxo, const uint32_t* __restrict__ cntG,
                                                  int shift) {
    __shared__ uint16_t wcnt[4][NBIN];
    __shared__ uint32_t runbase[NBIN];
    int t = threadIdx.x;
    int w = t >> 6, lane = t & 63;
    int bid = blockIdx.x;                 // 1536 = 8 xcd * (16 rows * 12 segs)
    int xcd = bid & 7;
    int k2 = bid >> 3;                    // 0..191
    int row = (xcd << 4) + (k2 & 15);
    int seg = k2 >> 4;                    // 0..11
    const uint32_t* cbase = cntG + ((size_t)row * NSEG + seg) * NBIN;
    #pragma unroll
    for (int k = 0; k < NBIN / 256; ++k) runbase[k * 256 + t] = cbase[k * 256 + t];
    for (int i = 0; i < SEGN / 256; ++i) {
        __syncthreads();
        #pragma unroll
        for (int k = 0; k < NBIN / 256; ++k)
            ((uint64_t*)wcnt)[k * 256 + t] = 0;      // zero 4*NBIN u16 = NBIN u64
        __syncthreads();
        uint64_t kv;
        if (MODE == 1) {
            const float* srcf = qkvv + (size_t)row * HW + (size_t)seg * SEGN;
            kv = (((uint64_t)f2s(srcf[i * 256 + t])) << 32) | (uint32_t)(seg * SEGN + i * 256 + t);
        } else {
            const uint64_t* src = in + (size_t)row * HW + (size_t)seg * SEGN;
            kv = src[i * 256 + t];
        }
        unsigned d = (unsigned)(kv >> shift) & (NBIN - 1);
        uint64_t peers = ~0ull;
        #pragma unroll
        for (int bit = 0; bit < 11; ++bit) {
            uint64_t bm = __ballot((d >> bit) & 1u);
            peers &= ((d >> bit) & 1u) ? bm : ~bm;
        }
        unsigned lanerank = (unsigned)__popcll(peers & ((1ull << lane) - 1ull));
        unsigned wtotal = (unsigned)__popcll(peers);
        if (lanerank == 0) wcnt[w][d] = (uint16_t)wtotal;
        __syncthreads();
        unsigned wpre = 0;
        #pragma unroll
        for (int ww = 0; ww < 4; ++ww) {
            unsigned cv = wcnt[ww][d];
            if (ww < w) wpre += cv;
        }
        unsigned pos = runbase[d] + wpre + lanerank;
        if (MODE == 2) {
            vso[(size_t)row * HW + pos] = s2f((uint32_t)(kv >> 32));
            idxo[(size_t)row * HW + pos] = (int)(kv & 0xFFFFFFFFull);
        } else {
            out[(size_t)row * HW + pos] = kv;
        }
        __syncthreads();
        #pragma unroll
        for (int k = 0; k < NBIN / 256; ++k) {
            int bn = k * 256 + t;
            runbase[bn] += (uint32_t)wcnt[0][bn] + wcnt[1][bn] + wcnt[2][bn] + wcnt[3][bn];
        }
    }
}

// ---------- K6d: gather q1,k1,q2,k2 into sorted order (v6: quad-gather) ----------
__global__ __launch_bounds__(1024) void k_gather4(const int* __restrict__ idxv, const float* __restrict__ qkvI,
                                                  float* __restrict__ g4) {
    int i = blockIdx.x;
    int row = (i & 7) * 16 + ((i >> 3) & 15);   // same-XCD blocks share a 16-row window
    int jh = i >> 7;                             // 0 or 1
    const int* irow = idxv + (size_t)row * HW + jh * (HW / 2);
    size_t S4 = (size_t)BB * CC * HW;            // 4718592
    int tid = threadIdx.x;
    const fx4* src = (const fx4*)(qkvI + (size_t)row * HW * 4);
    size_t dbase = (size_t)row * HW + jh * (HW / 2);
    float* d0 = g4 + dbase;
    float* d1 = d0 + S4;
    float* d2 = d0 + 2 * S4;
    float* d3 = d0 + 3 * S4;
    #pragma unroll 3
    for (int s = 0; s < 9; ++s) {
        int j = s * 2048 + tid * 2;
        int2 p = *(const int2*)&irow[j];
        fx4 a = src[p.x];
        fx4 b4 = src[p.y];
        fx2 w0 = {a.x, b4.x};
        fx2 w1 = {a.y, b4.y};
        fx2 w2 = {a.z, b4.z};
        fx2 w3 = {a.w, b4.w};
        __builtin_nontemporal_store(w0, (fx2*)&d0[j]);
        __builtin_nontemporal_store(w1, (fx2*)&d1[j]);
        __builtin_nontemporal_store(w2, (fx2*)&d2[j]);
        __builtin_nontemporal_store(w3, (fx2*)&d3[j]);
    }
}

// ---------- K7a: S partials + norm^2 partials, streaming from g4 ----------
__global__ __launch_bounds__(256) void k_attn_qk(const float* __restrict__ g4,
                                                 float* __restrict__ partS, float* __restrict__ partN) {
    __shared__ float Qs[16][68];
    __shared__ float Ks[16][68];
    __shared__ float nqs[4][64];
    __shared__ float nks[4][64];
    int tid = threadIdx.x;
    int ychunk = blockIdx.x;   // NCHUNK chunks of CHN
    int z = blockIdx.y;        // 16 = b(2) x h(4) x variant(2)
    int vi = z & 1, hh = (z >> 1) & 3, b = z >> 3;
    size_t S4 = (size_t)BB * CC * HW;
    const float* Q = g4 + (vi ? 2 * S4 : (size_t)0);
    const float* Kp = g4 + (vi ? 3 * S4 : S4);
    int ty = tid >> 4, tx = tid & 15;
    float acc[4][4] = {};
    float nq = 0.f, nk = 0.f;
    int d0 = tid & 63, kset = tid >> 6;
    int nbase0 = ychunk * CHN;
    for (int it = 0; it < CHN / 16; ++it) {
        int nb0 = nbase0 + it * 16;
        __syncthreads();
        #pragma unroll
        for (int l = 0; l < 4; ++l) {
            int idx = l * 256 + tid;
            int d = idx >> 4, kk = idx & 15;
            int n = nb0 + kk;
            int cch = hh * 16 + (d >> 2), f = d & 3;
            size_t off = ((size_t)(b * CC) + cch) * HW + (vi ? (size_t)(n * 4 + f) : (size_t)(f * NQ + n));
            Qs[kk][d] = Q[off];
            Ks[kk][d] = Kp[off];
        }
        __syncthreads();
        #pragma unroll
        for (int kk = 0; kk < 16; ++kk) {
            float4 av = *(const float4*)&Qs[kk][ty * 4];
            float4 bv = *(const float4*)&Ks[kk][tx * 4];
            float aa[4] = {av.x, av.y, av.z, av.w};
            float bb[4] = {bv.x, bv.y, bv.z, bv.w};
            #pragma unroll
            for (int i = 0; i < 4; ++i)
                #pragma unroll
                for (int j = 0; j < 4; ++j)
                    acc[i][j] = fmaf(aa[i], bb[j], acc[i][j]);
        }
        #pragma unroll
        for (int kk2 = 0; kk2 < 4; ++kk2) {
            float qv = Qs[kset * 4 + kk2][d0];
            float kv = Ks[kset * 4 + kk2][d0];
            nq = fmaf(qv, qv, nq);
            nk = fmaf(kv, kv, nk);
        }
    }
    size_t sb = ((size_t)z * NCHUNK + ychunk) * 4096;
    #pragma unroll
    for (int i = 0; i < 4; ++i)
        #pragma unroll
        for (int j = 0; j < 4; ++j)
            partS[sb + (size_t)(ty * 4 + i) * 64 + tx * 4 + j] = acc[i][j];
    nqs[kset][d0] = nq;
    nks[kset][d0] = nk;
    __syncthreads();
    if (tid < 64) {
        float sq = nqs[0][tid] + nqs[1][tid] + nqs[2][tid] + nqs[3][tid];
        float sk = nks[0][tid] + nks[1][tid] + nks[2][tid] + nks[3][tid];
        size_t nb2 = ((size_t)z * NCHUNK + ychunk) * 128;
        partN[nb2 + tid] = sq;
        partN[nb2 + 64 + tid] = sk;
    }
}

// ---------- K7b: reduce partials, normalize, exp, denom = rowsum+1 ; write attn^T ----------
__global__ __launch_bounds__(256) void k_attn_softmax(const float* __restrict__ partS,
                                                      const float* __restrict__ partN,
                                                      const float* __restrict__ temp, float* __restrict__ attnT) {
    __shared__ float nqv[64], nkv[64];
    __shared__ float pbuf[64][65];
    __shared__ float rred[64][4];
    __shared__ float rsum[64];
    int tid = threadIdx.x;
    int z = blockIdx.x;
    int hh = (z >> 1) & 3;
    if (tid < 128) {
        float s = 0.f;
        for (int ch = 0; ch < NCHUNK; ++ch) s += partN[((size_t)z * NCHUNK + ch) * 128 + tid];
        float nv = fmaxf(sqrtf(s), 1e-12f);
        if (tid < 64) nqv[tid] = nv; else nkv[tid - 64] = nv;
    }
    __syncthreads();
    float tf = temp[hh];
    int d = tid >> 2, qq = tid & 3;
    float psum = 0.f;
    for (int e = qq * 16; e < qq * 16 + 16; ++e) {
        float s = 0.f;
        for (int ch = 0; ch < NCHUNK; ++ch) s += partS[((size_t)z * NCHUNK + ch) * 4096 + (size_t)d * 64 + e];
        float p = expf(tf * s / (nqv[d] * nkv[e]));
        pbuf[d][e] = p;
        psum += p;
    }
    rred[d][qq] = psum;
    __syncthreads();
    if (tid < 64) rsum[tid] = rred[tid][0] + rred[tid][1] + rred[tid][2] + rred[tid][3] + 1.0f;
    __syncthreads();
    for (int e = qq * 16; e < qq * 16 + 16; ++e)
        attnT[(size_t)z * 4096 + (size_t)e * 64 + d] = pbuf[d][e] / rsum[d];
}

// ---------- K7c: O = attn * V, written back to (c, sorted-position) layout ----------
__global__ __launch_bounds__(256) void k_attn_av(const float* __restrict__ attnT, const float* __restrict__ vs,
                                                 float* __restrict__ O1, float* __restrict__ O2) {
    __shared__ float at_s[4096];
    int tid = threadIdx.x;
    int z = blockIdx.y;
    int vi = z & 1, hh = (z >> 1) & 3, b = z >> 3;
    for (int l = 0; l < 16; ++l) at_s[l * 256 + tid] = attnT[(size_t)z * 4096 + l * 256 + tid];
    __syncthreads();
    int n = blockIdx.x * 256 + tid;
    float acc[64];
    #pragma unroll
    for (int d = 0; d < 64; ++d) acc[d] = 0.f;
    for (int e = 0; e < 64; ++e) {
        int cch = hh * 16 + (e >> 2), f = e & 3;
        size_t p = vi ? (size_t)(n * 4 + f) : (size_t)(f * NQ + n);
        float vv = vs[((size_t)(b * CC) + cch) * HW + p];
        const float* ar = &at_s[e * 64];
        #pragma unroll
        for (int d4 = 0; d4 < 16; ++d4) {
            float4 a4 = *(const float4*)&ar[d4 * 4];
            acc[d4 * 4 + 0] = fmaf(a4.x, vv, acc[d4 * 4 + 0]);
            acc[d4 * 4 + 1] = fmaf(a4.y, vv, acc[d4 * 4 + 1]);
            acc[d4 * 4 + 2] = fmaf(a4.z, vv, acc[d4 * 4 + 2]);
            acc[d4 * 4 + 3] = fmaf(a4.w, vv, acc[d4 * 4 + 3]);
        }
    }
    float* Ob = vi ? O2 : O1;
    #pragma unroll
    for (int d = 0; d < 64; ++d) {
        int cch = hh * 16 + (d >> 2), f = d & 3;
        size_t p = vi ? (size_t)(n * 4 + f) : (size_t)(f * NQ + n);
        Ob[((size_t)(b * CC) + cch) * HW + p] = acc[d];
    }
}

// ---------- K8: product in sorted domain, scatter to original positions via idxv ----------
__global__ void k_prod_scatter(const float* __restrict__ O1, const float* __restrict__ O2,
                               const int* __restrict__ idxv, float* __restrict__ pu) {
    int j = blockIdx.x * 256 + threadIdx.x;
    int row = blockIdx.y;
    size_t o = (size_t)row * HW + j;
    int p = idxv[o];
    pu[(size_t)row * HW + p] = O1[o] * O2[o];
}

// ---------- K9: proj GEMM 64x64 ----------
__global__ __launch_bounds__(256) void k_gemm_proj(const float* __restrict__ wp, const float* __restrict__ pu,
                                                   float* __restrict__ op) {
    __shared__ float wt[2048];  // wt[c*32+mm] = wp[(mh*32+mm)*64+c]
    int tid = threadIdx.x;
    int mh = blockIdx.y, b = blockIdx.z;
    for (int l = 0; l < 8; ++l) {
        int i = l * 256 + tid;
        int mm = i >> 6, c = i & 63;
        wt[c * 32 + mm] = wp[(size_t)(mh * 32 + mm) * 64 + c];
    }
    __syncthreads();
    int n = blockIdx.x * 256 + tid;
    float acc[32];
    #pragma unroll
    for (int m = 0; m < 32; ++m) acc[m] = 0.f;
    const float* src = pu + (size_t)(b * CC) * HW + n;
    for (int c = 0; c < 64; ++c) {
        float xv = src[(size_t)c * HW];
        const float* wr = &wt[c * 32];
        #pragma unroll
        for (int m4 = 0; m4 < 8; ++m4) {
            float4 w4 = *(const float4*)&wr[m4 * 4];
            acc[m4 * 4 + 0] = fmaf(w4.x, xv, acc[m4 * 4 + 0]);
            acc[m4 * 4 + 1] = fmaf(w4.y, xv, acc[m4 * 4 + 1]);
            acc[m4 * 4 + 2] = fmaf(w4.z, xv, acc[m4 * 4 + 2]);
            acc[m4 * 4 + 3] = fmaf(w4.w, xv, acc[m4 * 4 + 3]);
        }
    }
    float* dst = op + ((size_t)(b * CC) + mh * 32) * HW + n;
    for (int m = 0; m < 32; ++m) dst[(size_t)m * HW] = acc[m];
}

// ---------- K10: spatial unsort scatter for c<32, copy c>=32 ----------
__global__ void k_final(const float* __restrict__ op, const int* __restrict__ idx_h,
                        const int* __restrict__ idx_w, float* __restrict__ out) {
    int i = blockIdx.x * 256 + threadIdx.x;
    int p = i % HW;
    int c = (i / HW) % CC;
    int b = i / (HW * CC);
    float v = op[i];
    if (c < CHF) {
        int h = p / IMW, w = p % IMW;
        size_t ib = ((size_t)(b * CHF) + c) * HW;
        int W0 = idx_w[ib + h * IMW + w];
        int H0 = idx_h[ib + h * IMW + W0];
        out[((size_t)(b * CC) + c) * HW + H0 * IMW + W0] = v;
    } else {
        out[i] = v;
    }
}

extern "C" void kernel_launch(void* const* d_in, const int* in_sizes, int n_in,
                              void* d_out, int out_size, void* d_ws, size_t ws_size,
                              hipStream_t stream) {
    (void)in_sizes; (void)n_in; (void)out_size; (void)ws_size;
    const float* x    = (const float*)d_in[0];
    const float* temp = (const float*)d_in[1];
    const float* wq   = (const float*)d_in[2];
    const float* wd3  = (const float*)d_in[3];
    const float* wd5  = (const float*)d_in[4];
    const float* wd7  = (const float*)d_in[5];
    const float* wf   = (const float*)d_in[6];
    const float* bf   = (const float*)d_in[7];
    const float* wp   = (const float*)d_in[8];
    float* out = (float*)d_out;
    float* ws = (float*)d_ws;

    // ---- workspace arena (~228 MiB) — aliasing as verified in Rounds 7/9 ----
    int*      idx_h = (int*)(ws + 0);
    int*      idx_w = (int*)(ws + 2359296);
    float*    A     = ws + 4718592;
    float*    slice = ws + 4718592;                    // over dead A
    float*    q     = ws + 12582912;
    float*    qkvI  = ws + 36175872;                   // ..55050240 — live until gather4 done
    float*    qkvV  = ws + 55050240;                   // ..59768832 — dead after radix pass 0
    int*      idxv  = (int*)(ws + 4718592);            // over dead slice: 4718592..9437184
    uint32_t* cntG  = (uint32_t*)(ws + 9437184);       // 128*12*2048 u32 = 3145728 — exact fit 9437184..12582912
    uint64_t* keyA  = (uint64_t*)(ws + 12582912);      // over dead q: ..22020096
    uint64_t* keyB  = (uint64_t*)(ws + 22020096);      // ..31457280
    float*    vs    = ws + 31457280;                   // ..36175872
    float*    g4    = ws + 12582912;                   // over dead keyA+keyB (after radix)
    float*    O1    = ws + 36175872;                   // over dead qkvI (after gather4)
    float*    O2    = ws + 40894464;
    float*    pu    = ws + 45613056;
    float*    op    = ws + 50331648;                   // written by k_gemm_proj
    float*    partS = ws + 55050240;                   // over dead qkvV (written by attn_qk)
    float*    partN = ws + 57147392;
    float*    attnT = ws + 57212928;                   // -> ends 57278464

    k_sort_h<<<768, 256, 0, stream>>>(x, A, idx_h);
    k_sort_w<<<768, 256, 0, stream>>>(A, idx_w);
    k_gemm_q<<<dim3(576, 5, 2), 256, 0, stream>>>(wq, A, x, q);

    for (int g = 0; g < 3; ++g) {
        for (int chunk = 0; chunk < 3; ++chunk) {
            int r0 = chunk * CROWS;
            if (g == 0)      k_dwconv<3><<<dim3(12, 320, 2), 256, 0, stream>>>(q, wd3, slice, r0);
            else if (g == 1) k_dwconv<5><<<dim3(12, 320, 2), 256, 0, stream>>>(q, wd5, slice, r0);
            else             k_dwconv<7><<<dim3(12, 320, 2), 256, 0, stream>>>(q, wd7, slice, r0);
            k_gemm_fuse<<<dim3(96, 5, 2), 256, 0, stream>>>(wf, slice, bf, qkvI, qkvV, g, r0);
        }
    }

    // 3 stable LSD passes of 11 bits over the value (bits 32..63).
    k_rcount<1><<<dim3(NSEG, 128), 256, 0, stream>>>(nullptr, qkvV, cntG, 32);
    k_rscan<<<128, 256, 0, stream>>>(cntG);
    k_rscatter<1><<<1536, 256, 0, stream>>>(nullptr, qkvV, keyB, nullptr, nullptr, cntG, 32);
    k_rcount<0><<<dim3(NSEG, 128), 256, 0, stream>>>(keyB, nullptr, cntG, 43);
    k_rscan<<<128, 256, 0, stream>>>(cntG);
    k_rscatter<0><<<1536, 256, 0, stream>>>(keyB, nullptr, keyA, nullptr, nullptr, cntG, 43);
    k_rcount<0><<<dim3(NSEG, 128), 256, 0, stream>>>(keyA, nullptr, cntG, 54);
    k_rscan<<<128, 256, 0, stream>>>(cntG);
    k_rscatter<2><<<1536, 256, 0, stream>>>(keyA, nullptr, nullptr, vs, idxv, cntG, 54);

    k_gather4<<<256, 1024, 0, stream>>>(idxv, qkvI, g4);

    k_attn_qk<<<dim3(NCHUNK, 16), 256, 0, stream>>>(g4, partS, partN);
    k_attn_softmax<<<16, 256, 0, stream>>>(partS, partN, temp, attnT);
    k_attn_av<<<dim3(36, 16), 256, 0, stream>>>(attnT, vs, O1, O2);

    k_prod_scatter<<<dim3(144, 128), 256, 0, stream>>>(O1, O2, idxv, pu);
    k_gemm_proj<<<dim3(144, 2, 2), 256, 0, stream>>>(wp, pu, op);
    k_final<<<18432, 256, 0, stream>>>(op, idx_h, idx_w, out);
}

// Round 13
// 1169.221 us; speedup vs baseline: 1.0498x; 1.0498x over previous
//
#include <hip/hip_runtime.h>
#include <stdint.h>
#include <stddef.h>

constexpr int IMH = 192;
constexpr int IMW = 192;
constexpr int HW  = 36864;   // 192*192
constexpr int BB  = 2;
constexpr int CC  = 64;
constexpr int CHF = 32;      // half channels (sorted part)
constexpr int C5  = 320;     // 5*CC
constexpr int NQ  = 9216;    // HW/4
constexpr int CROWS = 64;    // fuse-pipeline chunk rows
constexpr int CHWN  = CROWS * IMW;  // 12288 cols per chunk
constexpr int NCHUNK = 32;   // attn_qk n-chunks per z
constexpr int CHN = HW / 4 / NCHUNK;  // 288 n per chunk
constexpr int NSEG = 12;     // radix segments per row (cntG fits the free hole exactly)
constexpr int SEGN = HW / NSEG;      // 3072 elements per segment (= 12 * 256)
constexpr int NBIN = 2048;   // 11-bit radix

typedef float fx2 __attribute__((ext_vector_type(2)));
typedef float fx4 __attribute__((ext_vector_type(4)));
typedef _Float16 f16;
typedef _Float16 f16x8 __attribute__((ext_vector_type(8)));
typedef float f32x4 __attribute__((ext_vector_type(4)));

// ---------- float <-> monotone uint32 (order-preserving, invertible) ----------
static __device__ __forceinline__ uint32_t f2s(float f) {
    uint32_t u = __float_as_uint(f);
    return (u & 0x80000000u) ? ~u : (u | 0x80000000u);
}
static __device__ __forceinline__ float s2f(uint32_t s) {
    uint32_t u = (s & 0x80000000u) ? (s & 0x7FFFFFFFu) : ~s;
    return __uint_as_float(u);
}

// ---------- multi-column bitonic: 256 slots x 16 lanes-wide in LDS, 256 threads ----------
static __device__ __forceinline__ void bitonic256x16(uint64_t (*keys)[17], int tid) {
    int wl = tid & 15;
    int p0 = tid >> 4;
    for (unsigned k = 2; k <= 256; k <<= 1) {
        for (unsigned j = k >> 1; j; j >>= 1) {
            __syncthreads();
            #pragma unroll
            for (int it = 0; it < 8; ++it) {
                unsigned pp = (unsigned)(p0 + it * 16);
                unsigned i = ((pp & ~(j - 1)) << 1) | (pp & (j - 1));
                unsigned q = i | j;
                bool up = ((i & k) == 0);
                uint64_t a = keys[i][wl], b = keys[q][wl];
                if ((a > b) == up) { keys[i][wl] = b; keys[q][wl] = a; }
            }
        }
    }
    __syncthreads();
}

// ---------- K1: stable sort along H, tiled: 16 adjacent w-columns per block ----------
__global__ __launch_bounds__(256) void k_sort_h(const float* __restrict__ x, float* __restrict__ A,
                                                int* __restrict__ idx_h) {
    __shared__ uint64_t keys[256][17];
    int tid = threadIdx.x;
    int blk = blockIdx.x;                 // b*CHF*12 + c*12 + wt
    int wt = blk % 12;
    int c  = (blk / 12) % CHF;
    int b  = blk / (12 * CHF);
    int w0 = wt * 16;
    const float* base = x + ((size_t)(b * CC) + c) * HW + w0;
    #pragma unroll
    for (int l = 0; l < 12; ++l) {
        int idx = l * 256 + tid;          // 0..3071
        int h = idx >> 4, wl = idx & 15;
        keys[h][wl] = (((uint64_t)f2s(base[(size_t)h * IMW + wl])) << 32) | (uint32_t)h;
    }
    #pragma unroll
    for (int l = 0; l < 4; ++l) {         // pad slots 192..255
        int idx = l * 256 + tid;
        keys[192 + (idx >> 4)][idx & 15] = ~0ull;
    }
    bitonic256x16(keys, tid);
    float* ocol = A + ((size_t)(b * CC) + c) * HW + w0;
    int* icol = idx_h + ((size_t)(b * CHF) + c) * HW + w0;
    #pragma unroll
    for (int l = 0; l < 12; ++l) {
        int idx = l * 256 + tid;
        int h = idx >> 4, wl = idx & 15;
        uint64_t kk = keys[h][wl];
        ocol[(size_t)h * IMW + wl] = s2f((uint32_t)(kk >> 32));
        icol[(size_t)h * IMW + wl] = (int)(kk & 0xFFFFFFFFull);
    }
}

// ---------- K2: stable sort along W, tiled: 16 rows per block, in-place on A ----------
__global__ __launch_bounds__(256) void k_sort_w(float* __restrict__ A, int* __restrict__ idx_w) {
    __shared__ uint64_t keys[256][17];
    int tid = threadIdx.x;
    int blk = blockIdx.x;                 // b*CHF*12 + c*12 + ht
    int ht = blk % 12;
    int c  = (blk / 12) % CHF;
    int b  = blk / (12 * CHF);
    int h0 = ht * 16;
    float* base = A + ((size_t)(b * CC) + c) * HW + (size_t)h0 * IMW;
    #pragma unroll
    for (int l = 0; l < 12; ++l) {
        int idx = l * 256 + tid;          // 0..3071
        int hl = idx / 192, w = idx % 192;
        keys[w][hl] = (((uint64_t)f2s(base[(size_t)hl * IMW + w])) << 32) | (uint32_t)w;
    }
    #pragma unroll
    for (int l = 0; l < 4; ++l) {         // pad slots 192..255
        int idx = l * 256 + tid;
        keys[192 + (idx >> 4)][idx & 15] = ~0ull;
    }
    bitonic256x16(keys, tid);
    int* irow = idx_w + ((size_t)(b * CHF) + c) * HW + (size_t)h0 * IMW;
    #pragma unroll
    for (int l = 0; l < 12; ++l) {
        int idx = l * 256 + tid;
        int hl = idx / 192, w = idx % 192;
        uint64_t kk = keys[w][hl];
        base[(size_t)hl * IMW + w] = s2f((uint32_t)(kk >> 32));
        irow[(size_t)hl * IMW + w] = (int)(kk & 0xFFFFFFFFull);
    }
}

// ---------- K3: q = W_qkv(320x64) * A(64xHW) per batch ----------
__global__ __launch_bounds__(256) void k_gemm_q(const float* __restrict__ wq, const float* __restrict__ A,
                                                const float* __restrict__ x, float* __restrict__ q) {
    __shared__ float Wt[64][68];
    __shared__ float Xt[64][68];
    int tid = threadIdx.x;
    int n0 = blockIdx.x * 64, m0 = blockIdx.y * 64, b = blockIdx.z;
    for (int l = 0; l < 16; ++l) {
        int idx = l * 256 + tid;
        int cc = idx & 63, m = idx >> 6;
        Wt[cc][m] = wq[(size_t)(m0 + m) * 64 + cc];
    }
    for (int l = 0; l < 16; ++l) {
        int idx = l * 256 + tid;
        int n = idx & 63, cc = idx >> 6;
        const float* sp = (cc < CHF) ? A : x;
        Xt[cc][n] = sp[((size_t)(b * CC) + cc) * HW + n0 + n];
    }
    __syncthreads();
    int ty = tid >> 4, tx = tid & 15;
    float acc[4][4] = {};
    for (int cc = 0; cc < 64; ++cc) {
        float4 av = *(const float4*)&Wt[cc][ty * 4];
        float4 bv = *(const float4*)&Xt[cc][tx * 4];
        float aa[4] = {av.x, av.y, av.z, av.w};
        float bb[4] = {bv.x, bv.y, bv.z, bv.w};
        #pragma unroll
        for (int i = 0; i < 4; ++i)
            #pragma unroll
            for (int j = 0; j < 4; ++j)
                acc[i][j] = fmaf(aa[i], bb[j], acc[i][j]);
    }
    for (int i = 0; i < 4; ++i) {
        float4 o;
        o.x = acc[i][0]; o.y = acc[i][1]; o.z = acc[i][2]; o.w = acc[i][3];
        *(float4*)&q[((size_t)(b * C5) + m0 + ty * 4 + i) * HW + n0 + tx * 4] = o;
    }
}

// ---------- K4: depthwise conv KSxKS (zero pad) for a 64-row chunk starting at r0 ----------
template <int KS>
__global__ __launch_bounds__(256) void k_dwconv(const float* __restrict__ q, const float* __restrict__ wd,
                                                float* __restrict__ slice, int r0) {
    constexpr int PAD = KS / 2;
    constexpr int EXT = 32 + 2 * PAD;
    __shared__ float tile[EXT][EXT];
    int tid = threadIdx.x;
    int b = blockIdx.z, c = blockIdx.y;
    int t = blockIdx.x;                  // 12 tiles: 2 tile-rows x 6 tile-cols
    int ty0 = r0 + (t / 6) * 32, tx0 = (t % 6) * 32;
    const float* src = q + ((size_t)(b * C5) + c) * HW;
    for (int i = tid; i < EXT * EXT; i += 256) {
        int iy = i / EXT, ix = i % EXT;
        int gy = ty0 + iy - PAD, gx = tx0 + ix - PAD;
        float v = 0.f;
        if (gy >= 0 && gy < IMH && gx >= 0 && gx < IMW) v = src[gy * IMW + gx];
        tile[iy][ix] = v;
    }
    __syncthreads();
    float wreg[KS * KS];
    #pragma unroll
    for (int i = 0; i < KS * KS; ++i) wreg[i] = wd[(size_t)c * KS * KS + i];
    float* dst = slice + ((size_t)(b * C5) + c) * CHWN;
    #pragma unroll
    for (int k = 0; k < 4; ++k) {
        int pix = k * 256 + tid;
        int py = pix >> 5, px = pix & 31;
        float acc = 0.f;
        #pragma unroll
        for (int ky = 0; ky < KS; ++ky)
            #pragma unroll
            for (int kx = 0; kx < KS; ++kx)
                acc = fmaf(tile[py + ky][px + kx], wreg[ky * KS + kx], acc);
        dst[(ty0 - r0 + py) * IMW + tx0 + px] = acc;
    }
}

// ---------- K5: qkv(chunk) (+)= W_fuse[:, g*320:(g+1)*320] * slice(chunk) ----------
// v6: MFMA f16x2 + INTERLEAVED output layout for q1/k1/q2/k2 (quad per (c,j));
// v-plane contiguous in qkvV for the radix sort.
__global__ __launch_bounds__(256) void k_gemm_fuse(const float* __restrict__ wf,
                                                   const float* __restrict__ slice, const float* __restrict__ bias,
                                                   float* __restrict__ qkvI, float* __restrict__ qkvV,
                                                   int g, int r0) {
    __shared__ f16 Ah[64][40];
    __shared__ f16 Al[64][40];
    int tid = threadIdx.x;
    int n0 = blockIdx.x * 128, py = blockIdx.y, m0 = py * 64, b = blockIdx.z;
    int lane = tid & 63, wv = tid >> 6;
    int l15 = lane & 15, lg = lane >> 4;
    int nwave = n0 + wv * 32;                 // wave's 32-col n-strip
    int sm = tid >> 2, skr = (tid & 3) * 8;   // W staging: m=tid>>2, 8 consecutive k
    int gk = g * 320;
    f32x4 acc[4][2];
    #pragma unroll
    for (int i = 0; i < 4; ++i)
        #pragma unroll
        for (int j = 0; j < 2; ++j)
            acc[i][j] = (f32x4){0.f, 0.f, 0.f, 0.f};

    const float* xcol = slice + (size_t)(b * C5) * CHWN + nwave + l15;
    const float* wrow = wf + (size_t)(m0 + sm) * 960 + gk + skr;

    for (int k0 = 0; k0 < 320; k0 += 32) {
        if (k0) __syncthreads();
        // stage W tile: fp32 -> f16 hi/lo split in registers -> LDS
        {
            float4 w0 = *(const float4*)(wrow + k0);
            float4 w1 = *(const float4*)(wrow + k0 + 4);
            float wvv[8] = {w0.x, w0.y, w0.z, w0.w, w1.x, w1.y, w1.z, w1.w};
            f16x8 hv, lv;
            #pragma unroll
            for (int j = 0; j < 8; ++j) {
                f16 h = (f16)wvv[j];
                hv[j] = h;
                lv[j] = (f16)(wvv[j] - (float)h);
            }
            *(f16x8*)&Ah[sm][skr] = hv;
            *(f16x8*)&Al[sm][skr] = lv;
        }
        float xv[2][8];
        #pragma unroll
        for (int fn = 0; fn < 2; ++fn)
            #pragma unroll
            for (int j = 0; j < 8; ++j)
                xv[fn][j] = xcol[(size_t)(k0 + lg * 8 + j) * CHWN + fn * 16];
        __syncthreads();
        f16x8 bh[2], bl[2];
        #pragma unroll
        for (int fn = 0; fn < 2; ++fn)
            #pragma unroll
            for (int j = 0; j < 8; ++j) {
                float v = xv[fn][j];
                f16 h = (f16)v;
                bh[fn][j] = h;
                bl[fn][j] = (f16)(v - (float)h);
            }
        #pragma unroll
        for (int fm = 0; fm < 4; ++fm) {
            f16x8 ah = *(const f16x8*)&Ah[fm * 16 + l15][lg * 8];
            f16x8 al = *(const f16x8*)&Al[fm * 16 + l15][lg * 8];
            #pragma unroll
            for (int fn = 0; fn < 2; ++fn) {
                acc[fm][fn] = __builtin_amdgcn_mfma_f32_16x16x32_f16(ah, bh[fn], acc[fm][fn], 0, 0, 0);
                acc[fm][fn] = __builtin_amdgcn_mfma_f32_16x16x32_f16(ah, bl[fn], acc[fm][fn], 0, 0, 0);
                acc[fm][fn] = __builtin_amdgcn_mfma_f32_16x16x32_f16(al, bh[fn], acc[fm][fn], 0, 0, 0);
            }
        }
    }

    #pragma unroll
    for (int fm = 0; fm < 4; ++fm) {
        #pragma unroll
        for (int r = 0; r < 4; ++r) {
            int m = m0 + fm * 16 + lg * 4 + r;
            int cg = m & 63;
            size_t colb = (size_t)r0 * IMW + nwave + l15;
            if (py < 4) {
                float* bp = qkvI + ((size_t)(b * CC + cg) * HW) * 4 + py;
                if (g == 0) {
                    float bv = bias[m];
                    #pragma unroll
                    for (int fn = 0; fn < 2; ++fn)
                        bp[(colb + fn * 16) * 4] = acc[fm][fn][r] + bv;
                } else {
                    #pragma unroll
                    for (int fn = 0; fn < 2; ++fn)
                        bp[(colb + fn * 16) * 4] += acc[fm][fn][r];
                }
            } else {
                float* bp = qkvV + (size_t)(b * CC + cg) * HW;
                if (g == 0) {
                    float bv = bias[m];
                    #pragma unroll
                    for (int fn = 0; fn < 2; ++fn)
                        bp[colb + fn * 16] = acc[fm][fn][r] + bv;
                } else {
                    #pragma unroll
                    for (int fn = 0; fn < 2; ++fn)
                        bp[colb + fn * 16] += acc[fm][fn][r];
                }
            }
        }
    }
}

// ---------- K6b-1: per-(row,seg) 11-bit digit histogram ----------
// FIRST=1: read qkvV v-plane directly (key formed on the fly, shift==32).
template <int FIRST>
__global__ __launch_bounds__(256) void k_rcount(const uint64_t* __restrict__ in, const float* __restrict__ qkvv,
                                                uint32_t* __restrict__ cntG, int shift) {
    __shared__ uint32_t hist[NBIN];
    int t = threadIdx.x;
    int seg = blockIdx.x, row = blockIdx.y;
    #pragma unroll
    for (int k = 0; k < NBIN / 256; ++k) hist[k * 256 + t] = 0;
    __syncthreads();
    if (FIRST) {
        const float* srcf = qkvv + (size_t)row * HW + (size_t)seg * SEGN;
        #pragma unroll
        for (int i = 0; i < SEGN / 256; ++i) {
            unsigned d = f2s(srcf[i * 256 + t]) & (NBIN - 1);   // shift==32
            atomicAdd(&hist[d], 1u);
        }
    } else {
        const uint64_t* src = in + (size_t)row * HW + (size_t)seg * SEGN;
        #pragma unroll
        for (int i = 0; i < SEGN / 256; ++i) {
            unsigned d = (unsigned)(src[i * 256 + t] >> shift) & (NBIN - 1);
            atomicAdd(&hist[d], 1u);
        }
    }
    __syncthreads();
    uint32_t* dstc = cntG + ((size_t)row * NSEG + seg) * NBIN;
    #pragma unroll
    for (int k = 0; k < NBIN / 256; ++k) dstc[k * 256 + t] = hist[k * 256 + t];
}

// ---------- K6b-2: per-row two-level scan -> absolute dest base per (seg,digit) ----------
__global__ __launch_bounds__(256) void k_rscan(uint32_t* __restrict__ cntG) {
    __shared__ uint32_t tot[NBIN];
    __shared__ uint32_t gsum[256];
    __shared__ uint32_t gbase[256];
    int t = threadIdx.x;
    int row = blockIdx.x;
    uint32_t* base = cntG + (size_t)row * NSEG * NBIN;
    uint32_t loc = 0;
    #pragma unroll
    for (int k = 0; k < NBIN / 256; ++k) {
        int bn = t * (NBIN / 256) + k;
        uint32_t s = 0;
        for (int sg = 0; sg < NSEG; ++sg) s += base[sg * NBIN + bn];
        tot[bn] = s;
        loc += s;
    }
    gsum[t] = loc;
    __syncthreads();
    if (t == 0) {
        uint32_t acc = 0;
        for (int i = 0; i < 256; ++i) { uint32_t v = gsum[i]; gbase[i] = acc; acc += v; }
    }
    __syncthreads();
    uint32_t run = gbase[t];
    #pragma unroll
    for (int k = 0; k < NBIN / 256; ++k) {
        int bn = t * (NBIN / 256) + k;
        uint32_t tv = tot[bn];
        uint32_t r2 = run;
        for (int sg = 0; sg < NSEG; ++sg) {
            uint32_t cv = base[sg * NBIN + bn];
            base[sg * NBIN + bn] = r2;
            r2 += cv;
        }
        run += tv;
    }
}

// ---------- K6b-3: stable scatter (11-bit) v3: ballot rank + wave-ordered LDS atomics ----------
// Replaces the per-iteration wcnt zero + cross-wave scan + runbase update (the measured
// cost: dur was ~65us at BOTH 144MB and 210MB writes -> NOT BW-bound; VALU/LDS
// maintenance + 24.5KB LDS occupancy cap were the wall). Per peer-group the leader does
// ONE LDS atomicAdd(&runbase[d], wtotal) (returns old = group base, broadcast via shfl);
// stability across waves enforced by 4 barrier-separated wave turns (same total order
// as the old wcnt scan). LDS 24.5KB -> 8KB.
// MODE 0: key->key. MODE 1: qkvV->key. MODE 2: key->vs+idxv (unpack fused).
template <int MODE>
__global__ __launch_bounds__(256) void k_rscatter(const uint64_t* __restrict__ in, const float* __restrict__ qkvv,
                                                  uint64_t* __restrict__ out, float* __restrict__ vso,
                                                  int* __restrict__ idxo, const uint32_t* __restrict__ cntG,
                                                  int shift) {
    __shared__ uint32_t runbase[NBIN];
    int t = threadIdx.x;
    int w = t >> 6, lane = t & 63;
    int seg = blockIdx.x, row = blockIdx.y;
    const uint32_t* cbase = cntG + ((size_t)row * NSEG + seg) * NBIN;
    #pragma unroll
    for (int k = 0; k < NBIN / 256; ++k) runbase[k * 256 + t] = cbase[k * 256 + t];
    __syncthreads();
    for (int i = 0; i < SEGN / 256; ++i) {
        uint64_t kv;
        if (MODE == 1) {
            const float* srcf = qkvv + (size_t)row * HW + (size_t)seg * SEGN;
            kv = (((uint64_t)f2s(srcf[i * 256 + t])) << 32) | (uint32_t)(seg * SEGN + i * 256 + t);
        } else {
            const uint64_t* src = in + (size_t)row * HW + (size_t)seg * SEGN;
            kv = src[i * 256 + t];
        }
        unsigned d = (unsigned)(kv >> shift) & (NBIN - 1);
        uint64_t peers = ~0ull;
        #pragma unroll
        for (int bit = 0; bit < 11; ++bit) {
            uint64_t bm = __ballot((d >> bit) & 1u);
            peers &= ((d >> bit) & 1u) ? bm : ~bm;
        }
        unsigned lanerank = (unsigned)__popcll(peers & ((1ull << lane) - 1ull));
        unsigned wtotal = (unsigned)__popcll(peers);
        int leaderlane = __ffsll((unsigned long long)peers) - 1;
        unsigned base = 0;
        #pragma unroll
        for (int ww = 0; ww < 4; ++ww) {
            if (w == ww && lanerank == 0)
                base = atomicAdd(&runbase[d], wtotal);
            __syncthreads();
        }
        base = (unsigned)__shfl((int)base, leaderlane);
        unsigned pos = base + lanerank;
        if (MODE == 2) {
            vso[(size_t)row * HW + pos] = s2f((uint32_t)(kv >> 32));
            idxo[(size_t)row * HW + pos] = (int)(kv & 0xFFFFFFFFull);
        } else {
            out[(size_t)row * HW + pos] = kv;
        }
    }
}

// ---------- K6d: gather q1,k1,q2,k2 into sorted order (v6: quad-gather) ----------
__global__ __launch_bounds__(1024) void k_gather4(const int* __restrict__ idxv, const float* __restrict__ qkvI,
                                                  float* __restrict__ g4) {
    int i = blockIdx.x;
    int row = (i & 7) * 16 + ((i >> 3) & 15);   // same-XCD blocks share a 16-row window
    int jh = i >> 7;                             // 0 or 1
    const int* irow = idxv + (size_t)row * HW + jh * (HW / 2);
    size_t S4 = (size_t)BB * CC * HW;            // 4718592
    int tid = threadIdx.x;
    const fx4* src = (const fx4*)(qkvI + (size_t)row * HW * 4);
    size_t dbase = (size_t)row * HW + jh * (HW / 2);
    float* d0 = g4 + dbase;
    float* d1 = d0 + S4;
    float* d2 = d0 + 2 * S4;
    float* d3 = d0 + 3 * S4;
    #pragma unroll 3
    for (int s = 0; s < 9; ++s) {
        int j = s * 2048 + tid * 2;
        int2 p = *(const int2*)&irow[j];
        fx4 a = src[p.x];
        fx4 b4 = src[p.y];
        fx2 w0 = {a.x, b4.x};
        fx2 w1 = {a.y, b4.y};
        fx2 w2 = {a.z, b4.z};
        fx2 w3 = {a.w, b4.w};
        __builtin_nontemporal_store(w0, (fx2*)&d0[j]);
        __builtin_nontemporal_store(w1, (fx2*)&d1[j]);
        __builtin_nontemporal_store(w2, (fx2*)&d2[j]);
        __builtin_nontemporal_store(w3, (fx2*)&d3[j]);
    }
}

// ---------- K7a: S partials + norm^2 partials, streaming from g4 ----------
__global__ __launch_bounds__(256) void k_attn_qk(const float* __restrict__ g4,
                                                 float* __restrict__ partS, float* __restrict__ partN) {
    __shared__ float Qs[16][68];
    __shared__ float Ks[16][68];
    __shared__ float nqs[4][64];
    __shared__ float nks[4][64];
    int tid = threadIdx.x;
    int ychunk = blockIdx.x;   // NCHUNK chunks of CHN
    int z = blockIdx.y;        // 16 = b(2) x h(4) x variant(2)
    int vi = z & 1, hh = (z >> 1) & 3, b = z >> 3;
    size_t S4 = (size_t)BB * CC * HW;
    const float* Q = g4 + (vi ? 2 * S4 : (size_t)0);
    const float* Kp = g4 + (vi ? 3 * S4 : S4);
    int ty = tid >> 4, tx = tid & 15;
    float acc[4][4] = {};
    float nq = 0.f, nk = 0.f;
    int d0 = tid & 63, kset = tid >> 6;
    int nbase0 = ychunk * CHN;
    for (int it = 0; it < CHN / 16; ++it) {
        int nb0 = nbase0 + it * 16;
        __syncthreads();
        #pragma unroll
        for (int l = 0; l < 4; ++l) {
            int idx = l * 256 + tid;
            int d = idx >> 4, kk = idx & 15;
            int n = nb0 + kk;
            int cch = hh * 16 + (d >> 2), f = d & 3;
            size_t off = ((size_t)(b * CC) + cch) * HW + (vi ? (size_t)(n * 4 + f) : (size_t)(f * NQ + n));
            Qs[kk][d] = Q[off];
            Ks[kk][d] = Kp[off];
        }
        __syncthreads();
        #pragma unroll
        for (int kk = 0; kk < 16; ++kk) {
            float4 av = *(const float4*)&Qs[kk][ty * 4];
            float4 bv = *(const float4*)&Ks[kk][tx * 4];
            float aa[4] = {av.x, av.y, av.z, av.w};
            float bb[4] = {bv.x, bv.y, bv.z, bv.w};
            #pragma unroll
            for (int i = 0; i < 4; ++i)
                #pragma unroll
                for (int j = 0; j < 4; ++j)
                    acc[i][j] = fmaf(aa[i], bb[j], acc[i][j]);
        }
        #pragma unroll
        for (int kk2 = 0; kk2 < 4; ++kk2) {
            float qv = Qs[kset * 4 + kk2][d0];
            float kv = Ks[kset * 4 + kk2][d0];
            nq = fmaf(qv, qv, nq);
            nk = fmaf(kv, kv, nk);
        }
    }
    size_t sb = ((size_t)z * NCHUNK + ychunk) * 4096;
    #pragma unroll
    for (int i = 0; i < 4; ++i)
        #pragma unroll
        for (int j = 0; j < 4; ++j)
            partS[sb + (size_t)(ty * 4 + i) * 64 + tx * 4 + j] = acc[i][j];
    nqs[kset][d0] = nq;
    nks[kset][d0] = nk;
    __syncthreads();
    if (tid < 64) {
        float sq = nqs[0][tid] + nqs[1][tid] + nqs[2][tid] + nqs[3][tid];
        float sk = nks[0][tid] + nks[1][tid] + nks[2][tid] + nks[3][tid];
        size_t nb2 = ((size_t)z * NCHUNK + ychunk) * 128;
        partN[nb2 + tid] = sq;
        partN[nb2 + 64 + tid] = sk;
    }
}

// ---------- K7b: reduce partials, normalize, exp, denom = rowsum+1 ; write attn^T ----------
__global__ __launch_bounds__(256) void k_attn_softmax(const float* __restrict__ partS,
                                                      const float* __restrict__ partN,
                                                      const float* __restrict__ temp, float* __restrict__ attnT) {
    __shared__ float nqv[64], nkv[64];
    __shared__ float pbuf[64][65];
    __shared__ float rred[64][4];
    __shared__ float rsum[64];
    int tid = threadIdx.x;
    int z = blockIdx.x;
    int hh = (z >> 1) & 3;
    if (tid < 128) {
        float s = 0.f;
        for (int ch = 0; ch < NCHUNK; ++ch) s += partN[((size_t)z * NCHUNK + ch) * 128 + tid];
        float nv = fmaxf(sqrtf(s), 1e-12f);
        if (tid < 64) nqv[tid] = nv; else nkv[tid - 64] = nv;
    }
    __syncthreads();
    float tf = temp[hh];
    int d = tid >> 2, qq = tid & 3;
    float psum = 0.f;
    for (int e = qq * 16; e < qq * 16 + 16; ++e) {
        float s = 0.f;
        for (int ch = 0; ch < NCHUNK; ++ch) s += partS[((size_t)z * NCHUNK + ch) * 4096 + (size_t)d * 64 + e];
        float p = expf(tf * s / (nqv[d] * nkv[e]));
        pbuf[d][e] = p;
        psum += p;
    }
    rred[d][qq] = psum;
    __syncthreads();
    if (tid < 64) rsum[tid] = rred[tid][0] + rred[tid][1] + rred[tid][2] + rred[tid][3] + 1.0f;
    __syncthreads();
    for (int e = qq * 16; e < qq * 16 + 16; ++e)
        attnT[(size_t)z * 4096 + (size_t)e * 64 + d] = pbuf[d][e] / rsum[d];
}

// ---------- K7c: O = attn * V, written back to (c, sorted-position) layout ----------
__global__ __launch_bounds__(256) void k_attn_av(const float* __restrict__ attnT, const float* __restrict__ vs,
                                                 float* __restrict__ O1, float* __restrict__ O2) {
    __shared__ float at_s[4096];
    int tid = threadIdx.x;
    int z = blockIdx.y;
    int vi = z & 1, hh = (z >> 1) & 3, b = z >> 3;
    for (int l = 0; l < 16; ++l) at_s[l * 256 + tid] = attnT[(size_t)z * 4096 + l * 256 + tid];
    __syncthreads();
    int n = blockIdx.x * 256 + tid;
    float acc[64];
    #pragma unroll
    for (int d = 0; d < 64; ++d) acc[d] = 0.f;
    for (int e = 0; e < 64; ++e) {
        int cch = hh * 16 + (e >> 2), f = e & 3;
        size_t p = vi ? (size_t)(n * 4 + f) : (size_t)(f * NQ + n);
        float vv = vs[((size_t)(b * CC) + cch) * HW + p];
        const float* ar = &at_s[e * 64];
        #pragma unroll
        for (int d4 = 0; d4 < 16; ++d4) {
            float4 a4 = *(const float4*)&ar[d4 * 4];
            acc[d4 * 4 + 0] = fmaf(a4.x, vv, acc[d4 * 4 + 0]);
            acc[d4 * 4 + 1] = fmaf(a4.y, vv, acc[d4 * 4 + 1]);
            acc[d4 * 4 + 2] = fmaf(a4.z, vv, acc[d4 * 4 + 2]);
            acc[d4 * 4 + 3] = fmaf(a4.w, vv, acc[d4 * 4 + 3]);
        }
    }
    float* Ob = vi ? O2 : O1;
    #pragma unroll
    for (int d = 0; d < 64; ++d) {
        int cch = hh * 16 + (d >> 2), f = d & 3;
        size_t p = vi ? (size_t)(n * 4 + f) : (size_t)(f * NQ + n);
        Ob[((size_t)(b * CC) + cch) * HW + p] = acc[d];
    }
}

// ---------- K8: product in sorted domain, scatter to original positions via idxv ----------
__global__ void k_prod_scatter(const float* __restrict__ O1, const float* __restrict__ O2,
                               const int* __restrict__ idxv, float* __restrict__ pu) {
    int j = blockIdx.x * 256 + threadIdx.x;
    int row = blockIdx.y;
    size_t o = (size_t)row * HW + j;
    int p = idxv[o];
    pu[(size_t)row * HW + p] = O1[o] * O2[o];
}

// ---------- K9: proj GEMM 64x64 ----------
__global__ __launch_bounds__(256) void k_gemm_proj(const float* __restrict__ wp, const float* __restrict__ pu,
                                                   float* __restrict__ op) {
    __shared__ float wt[2048];  // wt[c*32+mm] = wp[(mh*32+mm)*64+c]
    int tid = threadIdx.x;
    int mh = blockIdx.y, b = blockIdx.z;
    for (int l = 0; l < 8; ++l) {
        int i = l * 256 + tid;
        int mm = i >> 6, c = i & 63;
        wt[c * 32 + mm] = wp[(size_t)(mh * 32 + mm) * 64 + c];
    }
    __syncthreads();
    int n = blockIdx.x * 256 + tid;
    float acc[32];
    #pragma unroll
    for (int m = 0; m < 32; ++m) acc[m] = 0.f;
    const float* src = pu + (size_t)(b * CC) * HW + n;
    for (int c = 0; c < 64; ++c) {
        float xv = src[(size_t)c * HW];
        const float* wr = &wt[c * 32];
        #pragma unroll
        for (int m4 = 0; m4 < 8; ++m4) {
            float4 w4 = *(const float4*)&wr[m4 * 4];
            acc[m4 * 4 + 0] = fmaf(w4.x, xv, acc[m4 * 4 + 0]);
            acc[m4 * 4 + 1] = fmaf(w4.y, xv, acc[m4 * 4 + 1]);
            acc[m4 * 4 + 2] = fmaf(w4.z, xv, acc[m4 * 4 + 2]);
            acc[m4 * 4 + 3] = fmaf(w4.w, xv, acc[m4 * 4 + 3]);
        }
    }
    float* dst = op + ((size_t)(b * CC) + mh * 32) * HW + n;
    for (int m = 0; m < 32; ++m) dst[(size_t)m * HW] = acc[m];
}

// ---------- K10: spatial unsort scatter for c<32, copy c>=32 ----------
__global__ void k_final(const float* __restrict__ op, const int* __restrict__ idx_h,
                        const int* __restrict__ idx_w, float* __restrict__ out) {
    int i = blockIdx.x * 256 + threadIdx.x;
    int p = i % HW;
    int c = (i / HW) % CC;
    int b = i / (HW * CC);
    float v = op[i];
    if (c < CHF) {
        int h = p / IMW, w = p % IMW;
        size_t ib = ((size_t)(b * CHF) + c) * HW;
        int W0 = idx_w[ib + h * IMW + w];
        int H0 = idx_h[ib + h * IMW + W0];
        out[((size_t)(b * CC) + c) * HW + H0 * IMW + W0] = v;
    } else {
        out[i] = v;
    }
}

extern "C" void kernel_launch(void* const* d_in, const int* in_sizes, int n_in,
                              void* d_out, int out_size, void* d_ws, size_t ws_size,
                              hipStream_t stream) {
    (void)in_sizes; (void)n_in; (void)out_size; (void)ws_size;
    const float* x    = (const float*)d_in[0];
    const float* temp = (const float*)d_in[1];
    const float* wq   = (const float*)d_in[2];
    const float* wd3  = (const float*)d_in[3];
    const float* wd5  = (const float*)d_in[4];
    const float* wd7  = (const float*)d_in[5];
    const float* wf   = (const float*)d_in[6];
    const float* bf   = (const float*)d_in[7];
    const float* wp   = (const float*)d_in[8];
    float* out = (float*)d_out;
    float* ws = (float*)d_ws;

    // ---- workspace arena (~228 MiB) — aliasing as verified in Rounds 7/9 ----
    int*      idx_h = (int*)(ws + 0);
    int*      idx_w = (int*)(ws + 2359296);
    float*    A     = ws + 4718592;
    float*    slice = ws + 4718592;                    // over dead A
    float*    q     = ws + 12582912;
    float*    qkvI  = ws + 36175872;                   // ..55050240 — live until gather4 done
    float*    qkvV  = ws + 55050240;                   // ..59768832 — dead after radix pass 0
    int*      idxv  = (int*)(ws + 4718592);            // over dead slice: 4718592..9437184
    uint32_t* cntG  = (uint32_t*)(ws + 9437184);       // 128*12*2048 u32 = 3145728 — exact fit 9437184..12582912
    uint64_t* keyA  = (uint64_t*)(ws + 12582912);      // over dead q: ..22020096
    uint64_t* keyB  = (uint64_t*)(ws + 22020096);      // ..31457280
    float*    vs    = ws + 31457280;                   // ..36175872
    float*    g4    = ws + 12582912;                   // over dead keyA+keyB (after radix)
    float*    O1    = ws + 36175872;                   // over dead qkvI (after gather4)
    float*    O2    = ws + 40894464;
    float*    pu    = ws + 45613056;
    float*    op    = ws + 50331648;                   // written by k_gemm_proj
    float*    partS = ws + 55050240;                   // over dead qkvV (written by attn_qk)
    float*    partN = ws + 57147392;
    float*    attnT = ws + 57212928;                   // -> ends 57278464

    k_sort_h<<<768, 256, 0, stream>>>(x, A, idx_h);
    k_sort_w<<<768, 256, 0, stream>>>(A, idx_w);
    k_gemm_q<<<dim3(576, 5, 2), 256, 0, stream>>>(wq, A, x, q);

    for (int g = 0; g < 3; ++g) {
        for (int chunk = 0; chunk < 3; ++chunk) {
            int r0 = chunk * CROWS;
            if (g == 0)      k_dwconv<3><<<dim3(12, 320, 2), 256, 0, stream>>>(q, wd3, slice, r0);
            else if (g == 1) k_dwconv<5><<<dim3(12, 320, 2), 256, 0, stream>>>(q, wd5, slice, r0);
            else             k_dwconv<7><<<dim3(12, 320, 2), 256, 0, stream>>>(q, wd7, slice, r0);
            k_gemm_fuse<<<dim3(96, 5, 2), 256, 0, stream>>>(wf, slice, bf, qkvI, qkvV, g, r0);
        }
    }

    // 3 stable LSD passes of 11 bits over the value (bits 32..63).
    k_rcount<1><<<dim3(NSEG, 128), 256, 0, stream>>>(nullptr, qkvV, cntG, 32);
    k_rscan<<<128, 256, 0, stream>>>(cntG);
    k_rscatter<1><<<dim3(NSEG, 128), 256, 0, stream>>>(nullptr, qkvV, keyB, nullptr, nullptr, cntG, 32);
    k_rcount<0><<<dim3(NSEG, 128), 256, 0, stream>>>(keyB, nullptr, cntG, 43);
    k_rscan<<<128, 256, 0, stream>>>(cntG);
    k_rscatter<0><<<dim3(NSEG, 128), 256, 0, stream>>>(keyB, nullptr, keyA, nullptr, nullptr, cntG, 43);
    k_rcount<0><<<dim3(NSEG, 128), 256, 0, stream>>>(keyA, nullptr, cntG, 54);
    k_rscan<<<128, 256, 0, stream>>>(cntG);
    k_rscatter<2><<<dim3(NSEG, 128), 256, 0, stream>>>(keyA, nullptr, nullptr, vs, idxv, cntG, 54);

    k_gather4<<<256, 1024, 0, stream>>>(idxv, qkvI, g4);

    k_attn_qk<<<dim3(NCHUNK, 16), 256, 0, stream>>>(g4, partS, partN);
    k_attn_softmax<<<16, 256, 0, stream>>>(partS, partN, temp, attnT);
    k_attn_av<<<dim3(36, 16), 256, 0, stream>>>(attnT, vs, O1, O2);

    k_prod_scatter<<<dim3(144, 128), 256, 0, stream>>>(O1, O2, idxv, pu);
    k_gemm_proj<<<dim3(144, 2, 2), 256, 0, stream>>>(wp, pu, op);
    k_final<<<18432, 256, 0, stream>>>(op, idx_h, idx_w, out);
}

// Round 14
// 1165.851 us; speedup vs baseline: 1.0528x; 1.0029x over previous
//
#include <hip/hip_runtime.h>
#include <stdint.h>
#include <stddef.h>

constexpr int IMH = 192;
constexpr int IMW = 192;
constexpr int HW  = 36864;   // 192*192
constexpr int BB  = 2;
constexpr int CC  = 64;
constexpr int CHF = 32;      // half channels (sorted part)
constexpr int C5  = 320;     // 5*CC
constexpr int NQ  = 9216;    // HW/4
constexpr int CROWS = 64;    // fuse-pipeline chunk rows
constexpr int CHWN  = CROWS * IMW;  // 12288 cols per chunk
constexpr int NCHUNK = 32;   // attn_qk n-chunks per z
constexpr int CHN = HW / 4 / NCHUNK;  // 288 n per chunk
constexpr int NSEG = 12;     // radix segments per row (cntG fits the free hole exactly)
constexpr int SEGN = HW / NSEG;      // 3072 elements per segment (= 12 * 256)
constexpr int NBIN = 2048;   // 11-bit radix

typedef float fx2 __attribute__((ext_vector_type(2)));
typedef float fx4 __attribute__((ext_vector_type(4)));
typedef _Float16 f16;
typedef _Float16 f16x8 __attribute__((ext_vector_type(8)));
typedef float f32x4 __attribute__((ext_vector_type(4)));

// ---------- float <-> monotone uint32 (order-preserving, invertible) ----------
static __device__ __forceinline__ uint32_t f2s(float f) {
    uint32_t u = __float_as_uint(f);
    return (u & 0x80000000u) ? ~u : (u | 0x80000000u);
}
static __device__ __forceinline__ float s2f(uint32_t s) {
    uint32_t u = (s & 0x80000000u) ? (s & 0x7FFFFFFFu) : ~s;
    return __uint_as_float(u);
}

// ---------- multi-column bitonic: 256 slots x 16 lanes-wide in LDS, 256 threads ----------
static __device__ __forceinline__ void bitonic256x16(uint64_t (*keys)[17], int tid) {
    int wl = tid & 15;
    int p0 = tid >> 4;
    for (unsigned k = 2; k <= 256; k <<= 1) {
        for (unsigned j = k >> 1; j; j >>= 1) {
            __syncthreads();
            #pragma unroll
            for (int it = 0; it < 8; ++it) {
                unsigned pp = (unsigned)(p0 + it * 16);
                unsigned i = ((pp & ~(j - 1)) << 1) | (pp & (j - 1));
                unsigned q = i | j;
                bool up = ((i & k) == 0);
                uint64_t a = keys[i][wl], b = keys[q][wl];
                if ((a > b) == up) { keys[i][wl] = b; keys[q][wl] = a; }
            }
        }
    }
    __syncthreads();
}

// ---------- K1: stable sort along H, tiled: 16 adjacent w-columns per block ----------
__global__ __launch_bounds__(256) void k_sort_h(const float* __restrict__ x, float* __restrict__ A,
                                                int* __restrict__ idx_h) {
    __shared__ uint64_t keys[256][17];
    int tid = threadIdx.x;
    int blk = blockIdx.x;                 // b*CHF*12 + c*12 + wt
    int wt = blk % 12;
    int c  = (blk / 12) % CHF;
    int b  = blk / (12 * CHF);
    int w0 = wt * 16;
    const float* base = x + ((size_t)(b * CC) + c) * HW + w0;
    #pragma unroll
    for (int l = 0; l < 12; ++l) {
        int idx = l * 256 + tid;          // 0..3071
        int h = idx >> 4, wl = idx & 15;
        keys[h][wl] = (((uint64_t)f2s(base[(size_t)h * IMW + wl])) << 32) | (uint32_t)h;
    }
    #pragma unroll
    for (int l = 0; l < 4; ++l) {         // pad slots 192..255
        int idx = l * 256 + tid;
        keys[192 + (idx >> 4)][idx & 15] = ~0ull;
    }
    bitonic256x16(keys, tid);
    float* ocol = A + ((size_t)(b * CC) + c) * HW + w0;
    int* icol = idx_h + ((size_t)(b * CHF) + c) * HW + w0;
    #pragma unroll
    for (int l = 0; l < 12; ++l) {
        int idx = l * 256 + tid;
        int h = idx >> 4, wl = idx & 15;
        uint64_t kk = keys[h][wl];
        ocol[(size_t)h * IMW + wl] = s2f((uint32_t)(kk >> 32));
        icol[(size_t)h * IMW + wl] = (int)(kk & 0xFFFFFFFFull);
    }
}

// ---------- K2: stable sort along W, tiled: 16 rows per block, in-place on A ----------
__global__ __launch_bounds__(256) void k_sort_w(float* __restrict__ A, int* __restrict__ idx_w) {
    __shared__ uint64_t keys[256][17];
    int tid = threadIdx.x;
    int blk = blockIdx.x;                 // b*CHF*12 + c*12 + ht
    int ht = blk % 12;
    int c  = (blk / 12) % CHF;
    int b  = blk / (12 * CHF);
    int h0 = ht * 16;
    float* base = A + ((size_t)(b * CC) + c) * HW + (size_t)h0 * IMW;
    #pragma unroll
    for (int l = 0; l < 12; ++l) {
        int idx = l * 256 + tid;          // 0..3071
        int hl = idx / 192, w = idx % 192;
        keys[w][hl] = (((uint64_t)f2s(base[(size_t)hl * IMW + w])) << 32) | (uint32_t)w;
    }
    #pragma unroll
    for (int l = 0; l < 4; ++l) {         // pad slots 192..255
        int idx = l * 256 + tid;
        keys[192 + (idx >> 4)][idx & 15] = ~0ull;
    }
    bitonic256x16(keys, tid);
    int* irow = idx_w + ((size_t)(b * CHF) + c) * HW + (size_t)h0 * IMW;
    #pragma unroll
    for (int l = 0; l < 12; ++l) {
        int idx = l * 256 + tid;
        int hl = idx / 192, w = idx % 192;
        uint64_t kk = keys[w][hl];
        base[(size_t)hl * IMW + w] = s2f((uint32_t)(kk >> 32));
        irow[(size_t)hl * IMW + w] = (int)(kk & 0xFFFFFFFFull);
    }
}

// ---------- K3: q = W_qkv(320x64) * A(64xHW) per batch ----------
__global__ __launch_bounds__(256) void k_gemm_q(const float* __restrict__ wq, const float* __restrict__ A,
                                                const float* __restrict__ x, float* __restrict__ q) {
    __shared__ float Wt[64][68];
    __shared__ float Xt[64][68];
    int tid = threadIdx.x;
    int n0 = blockIdx.x * 64, m0 = blockIdx.y * 64, b = blockIdx.z;
    for (int l = 0; l < 16; ++l) {
        int idx = l * 256 + tid;
        int cc = idx & 63, m = idx >> 6;
        Wt[cc][m] = wq[(size_t)(m0 + m) * 64 + cc];
    }
    for (int l = 0; l < 16; ++l) {
        int idx = l * 256 + tid;
        int n = idx & 63, cc = idx >> 6;
        const float* sp = (cc < CHF) ? A : x;
        Xt[cc][n] = sp[((size_t)(b * CC) + cc) * HW + n0 + n];
    }
    __syncthreads();
    int ty = tid >> 4, tx = tid & 15;
    float acc[4][4] = {};
    for (int cc = 0; cc < 64; ++cc) {
        float4 av = *(const float4*)&Wt[cc][ty * 4];
        float4 bv = *(const float4*)&Xt[cc][tx * 4];
        float aa[4] = {av.x, av.y, av.z, av.w};
        float bb[4] = {bv.x, bv.y, bv.z, bv.w};
        #pragma unroll
        for (int i = 0; i < 4; ++i)
            #pragma unroll
            for (int j = 0; j < 4; ++j)
                acc[i][j] = fmaf(aa[i], bb[j], acc[i][j]);
    }
    for (int i = 0; i < 4; ++i) {
        float4 o;
        o.x = acc[i][0]; o.y = acc[i][1]; o.z = acc[i][2]; o.w = acc[i][3];
        *(float4*)&q[((size_t)(b * C5) + m0 + ty * 4 + i) * HW + n0 + tx * 4] = o;
    }
}

// ---------- K4: depthwise conv KSxKS (zero pad) for a 64-row chunk starting at r0 ----------
template <int KS>
__global__ __launch_bounds__(256) void k_dwconv(const float* __restrict__ q, const float* __restrict__ wd,
                                                float* __restrict__ slice, int r0) {
    constexpr int PAD = KS / 2;
    constexpr int EXT = 32 + 2 * PAD;
    __shared__ float tile[EXT][EXT];
    int tid = threadIdx.x;
    int b = blockIdx.z, c = blockIdx.y;
    int t = blockIdx.x;                  // 12 tiles: 2 tile-rows x 6 tile-cols
    int ty0 = r0 + (t / 6) * 32, tx0 = (t % 6) * 32;
    const float* src = q + ((size_t)(b * C5) + c) * HW;
    for (int i = tid; i < EXT * EXT; i += 256) {
        int iy = i / EXT, ix = i % EXT;
        int gy = ty0 + iy - PAD, gx = tx0 + ix - PAD;
        float v = 0.f;
        if (gy >= 0 && gy < IMH && gx >= 0 && gx < IMW) v = src[gy * IMW + gx];
        tile[iy][ix] = v;
    }
    __syncthreads();
    float wreg[KS * KS];
    #pragma unroll
    for (int i = 0; i < KS * KS; ++i) wreg[i] = wd[(size_t)c * KS * KS + i];
    float* dst = slice + ((size_t)(b * C5) + c) * CHWN;
    #pragma unroll
    for (int k = 0; k < 4; ++k) {
        int pix = k * 256 + tid;
        int py = pix >> 5, px = pix & 31;
        float acc = 0.f;
        #pragma unroll
        for (int ky = 0; ky < KS; ++ky)
            #pragma unroll
            for (int kx = 0; kx < KS; ++kx)
                acc = fmaf(tile[py + ky][px + kx], wreg[ky * KS + kx], acc);
        dst[(ty0 - r0 + py) * IMW + tx0 + px] = acc;
    }
}

// ---------- K5: qkv(chunk) (+)= W_fuse[:, g*320:(g+1)*320] * slice(chunk) ----------
// v6: MFMA f16x2 + INTERLEAVED output layout for q1/k1/q2/k2 (quad per (c,j));
// v-plane contiguous in qkvV for the radix sort.
__global__ __launch_bounds__(256) void k_gemm_fuse(const float* __restrict__ wf,
                                                   const float* __restrict__ slice, const float* __restrict__ bias,
                                                   float* __restrict__ qkvI, float* __restrict__ qkvV,
                                                   int g, int r0) {
    __shared__ f16 Ah[64][40];
    __shared__ f16 Al[64][40];
    int tid = threadIdx.x;
    int n0 = blockIdx.x * 128, py = blockIdx.y, m0 = py * 64, b = blockIdx.z;
    int lane = tid & 63, wv = tid >> 6;
    int l15 = lane & 15, lg = lane >> 4;
    int nwave = n0 + wv * 32;                 // wave's 32-col n-strip
    int sm = tid >> 2, skr = (tid & 3) * 8;   // W staging: m=tid>>2, 8 consecutive k
    int gk = g * 320;
    f32x4 acc[4][2];
    #pragma unroll
    for (int i = 0; i < 4; ++i)
        #pragma unroll
        for (int j = 0; j < 2; ++j)
            acc[i][j] = (f32x4){0.f, 0.f, 0.f, 0.f};

    const float* xcol = slice + (size_t)(b * C5) * CHWN + nwave + l15;
    const float* wrow = wf + (size_t)(m0 + sm) * 960 + gk + skr;

    for (int k0 = 0; k0 < 320; k0 += 32) {
        if (k0) __syncthreads();
        // stage W tile: fp32 -> f16 hi/lo split in registers -> LDS
        {
            float4 w0 = *(const float4*)(wrow + k0);
            float4 w1 = *(const float4*)(wrow + k0 + 4);
            float wvv[8] = {w0.x, w0.y, w0.z, w0.w, w1.x, w1.y, w1.z, w1.w};
            f16x8 hv, lv;
            #pragma unroll
            for (int j = 0; j < 8; ++j) {
                f16 h = (f16)wvv[j];
                hv[j] = h;
                lv[j] = (f16)(wvv[j] - (float)h);
            }
            *(f16x8*)&Ah[sm][skr] = hv;
            *(f16x8*)&Al[sm][skr] = lv;
        }
        float xv[2][8];
        #pragma unroll
        for (int fn = 0; fn < 2; ++fn)
            #pragma unroll
            for (int j = 0; j < 8; ++j)
                xv[fn][j] = xcol[(size_t)(k0 + lg * 8 + j) * CHWN + fn * 16];
        __syncthreads();
        f16x8 bh[2], bl[2];
        #pragma unroll
        for (int fn = 0; fn < 2; ++fn)
            #pragma unroll
            for (int j = 0; j < 8; ++j) {
                float v = xv[fn][j];
                f16 h = (f16)v;
                bh[fn][j] = h;
                bl[fn][j] = (f16)(v - (float)h);
            }
        #pragma unroll
        for (int fm = 0; fm < 4; ++fm) {
            f16x8 ah = *(const f16x8*)&Ah[fm * 16 + l15][lg * 8];
            f16x8 al = *(const f16x8*)&Al[fm * 16 + l15][lg * 8];
            #pragma unroll
            for (int fn = 0; fn < 2; ++fn) {
                acc[fm][fn] = __builtin_amdgcn_mfma_f32_16x16x32_f16(ah, bh[fn], acc[fm][fn], 0, 0, 0);
                acc[fm][fn] = __builtin_amdgcn_mfma_f32_16x16x32_f16(ah, bl[fn], acc[fm][fn], 0, 0, 0);
                acc[fm][fn] = __builtin_amdgcn_mfma_f32_16x16x32_f16(al, bh[fn], acc[fm][fn], 0, 0, 0);
            }
        }
    }

    #pragma unroll
    for (int fm = 0; fm < 4; ++fm) {
        #pragma unroll
        for (int r = 0; r < 4; ++r) {
            int m = m0 + fm * 16 + lg * 4 + r;
            int cg = m & 63;
            size_t colb = (size_t)r0 * IMW + nwave + l15;
            if (py < 4) {
                float* bp = qkvI + ((size_t)(b * CC + cg) * HW) * 4 + py;
                if (g == 0) {
                    float bv = bias[m];
                    #pragma unroll
                    for (int fn = 0; fn < 2; ++fn)
                        bp[(colb + fn * 16) * 4] = acc[fm][fn][r] + bv;
                } else {
                    #pragma unroll
                    for (int fn = 0; fn < 2; ++fn)
                        bp[(colb + fn * 16) * 4] += acc[fm][fn][r];
                }
            } else {
                float* bp = qkvV + (size_t)(b * CC + cg) * HW;
                if (g == 0) {
                    float bv = bias[m];
                    #pragma unroll
                    for (int fn = 0; fn < 2; ++fn)
                        bp[colb + fn * 16] = acc[fm][fn][r] + bv;
                } else {
                    #pragma unroll
                    for (int fn = 0; fn < 2; ++fn)
                        bp[colb + fn * 16] += acc[fm][fn][r];
                }
            }
        }
    }
}

// ---------- K6b-1: per-(row,seg) 11-bit digit histogram ----------
// FIRST=1: read qkvV v-plane directly (key formed on the fly, shift==32).
template <int FIRST>
__global__ __launch_bounds__(256) void k_rcount(const uint64_t* __restrict__ in, const float* __restrict__ qkvv,
                                                uint32_t* __restrict__ cntG, int shift) {
    __shared__ uint32_t hist[NBIN];
    int t = threadIdx.x;
    int seg = blockIdx.x, row = blockIdx.y;
    #pragma unroll
    for (int k = 0; k < NBIN / 256; ++k) hist[k * 256 + t] = 0;
    __syncthreads();
    if (FIRST) {
        const float* srcf = qkvv + (size_t)row * HW + (size_t)seg * SEGN;
        #pragma unroll
        for (int i = 0; i < SEGN / 256; ++i) {
            unsigned d = f2s(srcf[i * 256 + t]) & (NBIN - 1);   // shift==32
            atomicAdd(&hist[d], 1u);
        }
    } else {
        const uint64_t* src = in + (size_t)row * HW + (size_t)seg * SEGN;
        #pragma unroll
        for (int i = 0; i < SEGN / 256; ++i) {
            unsigned d = (unsigned)(src[i * 256 + t] >> shift) & (NBIN - 1);
            atomicAdd(&hist[d], 1u);
        }
    }
    __syncthreads();
    uint32_t* dstc = cntG + ((size_t)row * NSEG + seg) * NBIN;
    #pragma unroll
    for (int k = 0; k < NBIN / 256; ++k) dstc[k * 256 + t] = hist[k * 256 + t];
}

// ---------- K6b-2: per-row two-level scan -> absolute dest base per (seg,digit) ----------
__global__ __launch_bounds__(256) void k_rscan(uint32_t* __restrict__ cntG) {
    __shared__ uint32_t tot[NBIN];
    __shared__ uint32_t gsum[256];
    __shared__ uint32_t gbase[256];
    int t = threadIdx.x;
    int row = blockIdx.x;
    uint32_t* base = cntG + (size_t)row * NSEG * NBIN;
    uint32_t loc = 0;
    #pragma unroll
    for (int k = 0; k < NBIN / 256; ++k) {
        int bn = t * (NBIN / 256) + k;
        uint32_t s = 0;
        for (int sg = 0; sg < NSEG; ++sg) s += base[sg * NBIN + bn];
        tot[bn] = s;
        loc += s;
    }
    gsum[t] = loc;
    __syncthreads();
    if (t == 0) {
        uint32_t acc = 0;
        for (int i = 0; i < 256; ++i) { uint32_t v = gsum[i]; gbase[i] = acc; acc += v; }
    }
    __syncthreads();
    uint32_t run = gbase[t];
    #pragma unroll
    for (int k = 0; k < NBIN / 256; ++k) {
        int bn = t * (NBIN / 256) + k;
        uint32_t tv = tot[bn];
        uint32_t r2 = run;
        for (int sg = 0; sg < NSEG; ++sg) {
            uint32_t cv = base[sg * NBIN + bn];
            base[sg * NBIN + bn] = r2;
            r2 += cv;
        }
        run += tv;
    }
}

// ---------- K6b-3: stable scatter (11-bit) v4: preloaded keys + ballot rank + wave-ordered LDS atomics ----------
// v3 measurement: dur ~65us unchanged after removing all wcnt maintenance -> wall is the
// per-iteration serial chain (key load can't issue until previous iteration's barriers).
// v4: all 12 keys preloaded into registers up-front (fixed addresses, fully overlapped);
// loop body is pure ballot+atomic+write.
// MODE 0: key->key. MODE 1: qkvV->key. MODE 2: key->vs+idxv (unpack fused).
template <int MODE>
__global__ __launch_bounds__(256) void k_rscatter(const uint64_t* __restrict__ in, const float* __restrict__ qkvv,
                                                  uint64_t* __restrict__ out, float* __restrict__ vso,
                                                  int* __restrict__ idxo, const uint32_t* __restrict__ cntG,
                                                  int shift) {
    __shared__ uint32_t runbase[NBIN];
    int t = threadIdx.x;
    int w = t >> 6, lane = t & 63;
    int seg = blockIdx.x, row = blockIdx.y;
    const uint32_t* cbase = cntG + ((size_t)row * NSEG + seg) * NBIN;
    uint64_t kvp[SEGN / 256];
    if (MODE == 1) {
        const float* srcf = qkvv + (size_t)row * HW + (size_t)seg * SEGN;
        #pragma unroll
        for (int i = 0; i < SEGN / 256; ++i)
            kvp[i] = (((uint64_t)f2s(srcf[i * 256 + t])) << 32) | (uint32_t)(seg * SEGN + i * 256 + t);
    } else {
        const uint64_t* src = in + (size_t)row * HW + (size_t)seg * SEGN;
        #pragma unroll
        for (int i = 0; i < SEGN / 256; ++i)
            kvp[i] = src[i * 256 + t];
    }
    #pragma unroll
    for (int k = 0; k < NBIN / 256; ++k) runbase[k * 256 + t] = cbase[k * 256 + t];
    __syncthreads();
    #pragma unroll
    for (int i = 0; i < SEGN / 256; ++i) {
        uint64_t kv = kvp[i];
        unsigned d = (unsigned)(kv >> shift) & (NBIN - 1);
        uint64_t peers = ~0ull;
        #pragma unroll
        for (int bit = 0; bit < 11; ++bit) {
            uint64_t bm = __ballot((d >> bit) & 1u);
            peers &= ((d >> bit) & 1u) ? bm : ~bm;
        }
        unsigned lanerank = (unsigned)__popcll(peers & ((1ull << lane) - 1ull));
        unsigned wtotal = (unsigned)__popcll(peers);
        int leaderlane = __ffsll((unsigned long long)peers) - 1;
        unsigned base = 0;
        #pragma unroll
        for (int ww = 0; ww < 4; ++ww) {
            if (w == ww && lanerank == 0)
                base = atomicAdd(&runbase[d], wtotal);
            __syncthreads();
        }
        base = (unsigned)__shfl((int)base, leaderlane);
        unsigned pos = base + lanerank;
        if (MODE == 2) {
            vso[(size_t)row * HW + pos] = s2f((uint32_t)(kv >> 32));
            idxo[(size_t)row * HW + pos] = (int)(kv & 0xFFFFFFFFull);
        } else {
            out[(size_t)row * HW + pos] = kv;
        }
    }
}

// ---------- K6d: gather q1,k1,q2,k2 into sorted order (v7: quad-gather, 4-row L2 window) ----------
// v6 counters: FETCH 190MB = 2.5x compulsory (16-row quad window = 9.2MB > 4MB L2).
// v7: 512 blocks x 768 thr = exactly 2 blocks/CU (uniform residency); per XCD, each
// phase covers only 4 quad-rows = 2.3MB (L2-resident); 4 lockstep phases cover 16 rows.
// block = (xcd=i&7, rsub=(i>>3)&3, jseg=(i>>3)>>2 in 0..15); 2304 elem/phase = 3x768.
__global__ __launch_bounds__(768) void k_gather4(const int* __restrict__ idxv, const float* __restrict__ qkvI,
                                                 float* __restrict__ g4) {
    int i = blockIdx.x;
    int xcd = i & 7;
    int local = i >> 3;                          // 0..63
    int rsub = local & 3;
    int jseg = local >> 2;                       // 0..15
    size_t S4 = (size_t)BB * CC * HW;            // 4718592
    int tid = threadIdx.x;
    for (int ph = 0; ph < 4; ++ph) {
        int row = xcd * 16 + ph * 4 + rsub;
        const int* irow = idxv + (size_t)row * HW + jseg * 2304;
        const fx4* src = (const fx4*)(qkvI + (size_t)row * HW * 4);
        size_t dbase = (size_t)row * HW + jseg * 2304;
        float* d0 = g4 + dbase;
        float* d1 = d0 + S4;
        float* d2 = d0 + 2 * S4;
        float* d3 = d0 + 3 * S4;
        #pragma unroll
        for (int s = 0; s < 3; ++s) {
            int j = s * 768 + tid;
            int p = irow[j];
            fx4 a = src[p];
            __builtin_nontemporal_store(a.x, &d0[j]);
            __builtin_nontemporal_store(a.y, &d1[j]);
            __builtin_nontemporal_store(a.z, &d2[j]);
            __builtin_nontemporal_store(a.w, &d3[j]);
        }
        __syncthreads();                         // keep the XCD's blocks in the same phase
    }
}

// ---------- K7a: S partials + norm^2 partials, streaming from g4 ----------
__global__ __launch_bounds__(256) void k_attn_qk(const float* __restrict__ g4,
                                                 float* __restrict__ partS, float* __restrict__ partN) {
    __shared__ float Qs[16][68];
    __shared__ float Ks[16][68];
    __shared__ float nqs[4][64];
    __shared__ float nks[4][64];
    int tid = threadIdx.x;
    int ychunk = blockIdx.x;   // NCHUNK chunks of CHN
    int z = blockIdx.y;        // 16 = b(2) x h(4) x variant(2)
    int vi = z & 1, hh = (z >> 1) & 3, b = z >> 3;
    size_t S4 = (size_t)BB * CC * HW;
    const float* Q = g4 + (vi ? 2 * S4 : (size_t)0);
    const float* Kp = g4 + (vi ? 3 * S4 : S4);
    int ty = tid >> 4, tx = tid & 15;
    float acc[4][4] = {};
    float nq = 0.f, nk = 0.f;
    int d0 = tid & 63, kset = tid >> 6;
    int nbase0 = ychunk * CHN;
    for (int it = 0; it < CHN / 16; ++it) {
        int nb0 = nbase0 + it * 16;
        __syncthreads();
        #pragma unroll
        for (int l = 0; l < 4; ++l) {
            int idx = l * 256 + tid;
            int d = idx >> 4, kk = idx & 15;
            int n = nb0 + kk;
            int cch = hh * 16 + (d >> 2), f = d & 3;
            size_t off = ((size_t)(b * CC) + cch) * HW + (vi ? (size_t)(n * 4 + f) : (size_t)(f * NQ + n));
            Qs[kk][d] = Q[off];
            Ks[kk][d] = Kp[off];
        }
        __syncthreads();
        #pragma unroll
        for (int kk = 0; kk < 16; ++kk) {
            float4 av = *(const float4*)&Qs[kk][ty * 4];
            float4 bv = *(const float4*)&Ks[kk][tx * 4];
            float aa[4] = {av.x, av.y, av.z, av.w};
            float bb[4] = {bv.x, bv.y, bv.z, bv.w};
            #pragma unroll
            for (int i = 0; i < 4; ++i)
                #pragma unroll
                for (int j = 0; j < 4; ++j)
                    acc[i][j] = fmaf(aa[i], bb[j], acc[i][j]);
        }
        #pragma unroll
        for (int kk2 = 0; kk2 < 4; ++kk2) {
            float qv = Qs[kset * 4 + kk2][d0];
            float kv = Ks[kset * 4 + kk2][d0];
            nq = fmaf(qv, qv, nq);
            nk = fmaf(kv, kv, nk);
        }
    }
    size_t sb = ((size_t)z * NCHUNK + ychunk) * 4096;
    #pragma unroll
    for (int i = 0; i < 4; ++i)
        #pragma unroll
        for (int j = 0; j < 4; ++j)
            partS[sb + (size_t)(ty * 4 + i) * 64 + tx * 4 + j] = acc[i][j];
    nqs[kset][d0] = nq;
    nks[kset][d0] = nk;
    __syncthreads();
    if (tid < 64) {
        float sq = nqs[0][tid] + nqs[1][tid] + nqs[2][tid] + nqs[3][tid];
        float sk = nks[0][tid] + nks[1][tid] + nks[2][tid] + nks[3][tid];
        size_t nb2 = ((size_t)z * NCHUNK + ychunk) * 128;
        partN[nb2 + tid] = sq;
        partN[nb2 + 64 + tid] = sk;
    }
}

// ---------- K7b: reduce partials, normalize, exp, denom = rowsum+1 ; write attn^T ----------
__global__ __launch_bounds__(256) void k_attn_softmax(const float* __restrict__ partS,
                                                      const float* __restrict__ partN,
                                                      const float* __restrict__ temp, float* __restrict__ attnT) {
    __shared__ float nqv[64], nkv[64];
    __shared__ float pbuf[64][65];
    __shared__ float rred[64][4];
    __shared__ float rsum[64];
    int tid = threadIdx.x;
    int z = blockIdx.x;
    int hh = (z >> 1) & 3;
    if (tid < 128) {
        float s = 0.f;
        for (int ch = 0; ch < NCHUNK; ++ch) s += partN[((size_t)z * NCHUNK + ch) * 128 + tid];
        float nv = fmaxf(sqrtf(s), 1e-12f);
        if (tid < 64) nqv[tid] = nv; else nkv[tid - 64] = nv;
    }
    __syncthreads();
    float tf = temp[hh];
    int d = tid >> 2, qq = tid & 3;
    float psum = 0.f;
    for (int e = qq * 16; e < qq * 16 + 16; ++e) {
        float s = 0.f;
        for (int ch = 0; ch < NCHUNK; ++ch) s += partS[((size_t)z * NCHUNK + ch) * 4096 + (size_t)d * 64 + e];
        float p = expf(tf * s / (nqv[d] * nkv[e]));
        pbuf[d][e] = p;
        psum += p;
    }
    rred[d][qq] = psum;
    __syncthreads();
    if (tid < 64) rsum[tid] = rred[tid][0] + rred[tid][1] + rred[tid][2] + rred[tid][3] + 1.0f;
    __syncthreads();
    for (int e = qq * 16; e < qq * 16 + 16; ++e)
        attnT[(size_t)z * 4096 + (size_t)e * 64 + d] = pbuf[d][e] / rsum[d];
}

// ---------- K7c: O = attn * V, written back to (c, sorted-position) layout ----------
__global__ __launch_bounds__(256) void k_attn_av(const float* __restrict__ attnT, const float* __restrict__ vs,
                                                 float* __restrict__ O1, float* __restrict__ O2) {
    __shared__ float at_s[4096];
    int tid = threadIdx.x;
    int z = blockIdx.y;
    int vi = z & 1, hh = (z >> 1) & 3, b = z >> 3;
    for (int l = 0; l < 16; ++l) at_s[l * 256 + tid] = attnT[(size_t)z * 4096 + l * 256 + tid];
    __syncthreads();
    int n = blockIdx.x * 256 + tid;
    float acc[64];
    #pragma unroll
    for (int d = 0; d < 64; ++d) acc[d] = 0.f;
    for (int e = 0; e < 64; ++e) {
        int cch = hh * 16 + (e >> 2), f = e & 3;
        size_t p = vi ? (size_t)(n * 4 + f) : (size_t)(f * NQ + n);
        float vv = vs[((size_t)(b * CC) + cch) * HW + p];
        const float* ar = &at_s[e * 64];
        #pragma unroll
        for (int d4 = 0; d4 < 16; ++d4) {
            float4 a4 = *(const float4*)&ar[d4 * 4];
            acc[d4 * 4 + 0] = fmaf(a4.x, vv, acc[d4 * 4 + 0]);
            acc[d4 * 4 + 1] = fmaf(a4.y, vv, acc[d4 * 4 + 1]);
            acc[d4 * 4 + 2] = fmaf(a4.z, vv, acc[d4 * 4 + 2]);
            acc[d4 * 4 + 3] = fmaf(a4.w, vv, acc[d4 * 4 + 3]);
        }
    }
    float* Ob = vi ? O2 : O1;
    #pragma unroll
    for (int d = 0; d < 64; ++d) {
        int cch = hh * 16 + (d >> 2), f = d & 3;
        size_t p = vi ? (size_t)(n * 4 + f) : (size_t)(f * NQ + n);
        Ob[((size_t)(b * CC) + cch) * HW + p] = acc[d];
    }
}

// ---------- K8: product in sorted domain, scatter to original positions via idxv ----------
__global__ void k_prod_scatter(const float* __restrict__ O1, const float* __restrict__ O2,
                               const int* __restrict__ idxv, float* __restrict__ pu) {
    int j = blockIdx.x * 256 + threadIdx.x;
    int row = blockIdx.y;
    size_t o = (size_t)row * HW + j;
    int p = idxv[o];
    pu[(size_t)row * HW + p] = O1[o] * O2[o];
}

// ---------- K9: proj GEMM 64x64 ----------
__global__ __launch_bounds__(256) void k_gemm_proj(const float* __restrict__ wp, const float* __restrict__ pu,
                                                   float* __restrict__ op) {
    __shared__ float wt[2048];  // wt[c*32+mm] = wp[(mh*32+mm)*64+c]
    int tid = threadIdx.x;
    int mh = blockIdx.y, b = blockIdx.z;
    for (int l = 0; l < 8; ++l) {
        int i = l * 256 + tid;
        int mm = i >> 6, c = i & 63;
        wt[c * 32 + mm] = wp[(size_t)(mh * 32 + mm) * 64 + c];
    }
    __syncthreads();
    int n = blockIdx.x * 256 + tid;
    float acc[32];
    #pragma unroll
    for (int m = 0; m < 32; ++m) acc[m] = 0.f;
    const float* src = pu + (size_t)(b * CC) * HW + n;
    for (int c = 0; c < 64; ++c) {
        float xv = src[(size_t)c * HW];
        const float* wr = &wt[c * 32];
        #pragma unroll
        for (int m4 = 0; m4 < 8; ++m4) {
            float4 w4 = *(const float4*)&wr[m4 * 4];
            acc[m4 * 4 + 0] = fmaf(w4.x, xv, acc[m4 * 4 + 0]);
            acc[m4 * 4 + 1] = fmaf(w4.y, xv, acc[m4 * 4 + 1]);
            acc[m4 * 4 + 2] = fmaf(w4.z, xv, acc[m4 * 4 + 2]);
            acc[m4 * 4 + 3] = fmaf(w4.w, xv, acc[m4 * 4 + 3]);
        }
    }
    float* dst = op + ((size_t)(b * CC) + mh * 32) * HW + n;
    for (int m = 0; m < 32; ++m) dst[(size_t)m * HW] = acc[m];
}

// ---------- K10: spatial unsort scatter for c<32, copy c>=32 ----------
__global__ void k_final(const float* __restrict__ op, const int* __restrict__ idx_h,
                        const int* __restrict__ idx_w, float* __restrict__ out) {
    int i = blockIdx.x * 256 + threadIdx.x;
    int p = i % HW;
    int c = (i / HW) % CC;
    int b = i / (HW * CC);
    float v = op[i];
    if (c < CHF) {
        int h = p / IMW, w = p % IMW;
        size_t ib = ((size_t)(b * CHF) + c) * HW;
        int W0 = idx_w[ib + h * IMW + w];
        int H0 = idx_h[ib + h * IMW + W0];
        out[((size_t)(b * CC) + c) * HW + H0 * IMW + W0] = v;
    } else {
        out[i] = v;
    }
}

extern "C" void kernel_launch(void* const* d_in, const int* in_sizes, int n_in,
                              void* d_out, int out_size, void* d_ws, size_t ws_size,
                              hipStream_t stream) {
    (void)in_sizes; (void)n_in; (void)out_size; (void)ws_size;
    const float* x    = (const float*)d_in[0];
    const float* temp = (const float*)d_in[1];
    const float* wq   = (const float*)d_in[2];
    const float* wd3  = (const float*)d_in[3];
    const float* wd5  = (const float*)d_in[4];
    const float* wd7  = (const float*)d_in[5];
    const float* wf   = (const float*)d_in[6];
    const float* bf   = (const float*)d_in[7];
    const float* wp   = (const float*)d_in[8];
    float* out = (float*)d_out;
    float* ws = (float*)d_ws;

    // ---- workspace arena (~228 MiB) — aliasing as verified in Rounds 7/9 ----
    int*      idx_h = (int*)(ws + 0);
    int*      idx_w = (int*)(ws + 2359296);
    float*    A     = ws + 4718592;
    float*    slice = ws + 4718592;                    // over dead A
    float*    q     = ws + 12582912;
    float*    qkvI  = ws + 36175872;                   // ..55050240 — live until gather4 done
    float*    qkvV  = ws + 55050240;                   // ..59768832 — dead after radix pass 0
    int*      idxv  = (int*)(ws + 4718592);            // over dead slice: 4718592..9437184
    uint32_t* cntG  = (uint32_t*)(ws + 9437184);       // 128*12*2048 u32 = 3145728 — exact fit 9437184..12582912
    uint64_t* keyA  = (uint64_t*)(ws + 12582912);      // over dead q: ..22020096
    uint64_t* keyB  = (uint64_t*)(ws + 22020096);      // ..31457280
    float*    vs    = ws + 31457280;                   // ..36175872
    float*    g4    = ws + 12582912;                   // over dead keyA+keyB (after radix)
    float*    O1    = ws + 36175872;                   // over dead qkvI (after gather4)
    float*    O2    = ws + 40894464;
    float*    pu    = ws + 45613056;
    float*    op    = ws + 50331648;                   // written by k_gemm_proj
    float*    partS = ws + 55050240;                   // over dead qkvV (written by attn_qk)
    float*    partN = ws + 57147392;
    float*    attnT = ws + 57212928;                   // -> ends 57278464

    k_sort_h<<<768, 256, 0, stream>>>(x, A, idx_h);
    k_sort_w<<<768, 256, 0, stream>>>(A, idx_w);
    k_gemm_q<<<dim3(576, 5, 2), 256, 0, stream>>>(wq, A, x, q);

    for (int g = 0; g < 3; ++g) {
        for (int chunk = 0; chunk < 3; ++chunk) {
            int r0 = chunk * CROWS;
            if (g == 0)      k_dwconv<3><<<dim3(12, 320, 2), 256, 0, stream>>>(q, wd3, slice, r0);
            else if (g == 1) k_dwconv<5><<<dim3(12, 320, 2), 256, 0, stream>>>(q, wd5, slice, r0);
            else             k_dwconv<7><<<dim3(12, 320, 2), 256, 0, stream>>>(q, wd7, slice, r0);
            k_gemm_fuse<<<dim3(96, 5, 2), 256, 0, stream>>>(wf, slice, bf, qkvI, qkvV, g, r0);
        }
    }

    // 3 stable LSD passes of 11 bits over the value (bits 32..63).
    k_rcount<1><<<dim3(NSEG, 128), 256, 0, stream>>>(nullptr, qkvV, cntG, 32);
    k_rscan<<<128, 256, 0, stream>>>(cntG);
    k_rscatter<1><<<dim3(NSEG, 128), 256, 0, stream>>>(nullptr, qkvV, keyB, nullptr, nullptr, cntG, 32);
    k_rcount<0><<<dim3(NSEG, 128), 256, 0, stream>>>(keyB, nullptr, cntG, 43);
    k_rscan<<<128, 256, 0, stream>>>(cntG);
    k_rscatter<0><<<dim3(NSEG, 128), 256, 0, stream>>>(keyB, nullptr, keyA, nullptr, nullptr, cntG, 43);
    k_rcount<0><<<dim3(NSEG, 128), 256, 0, stream>>>(keyA, nullptr, cntG, 54);
    k_rscan<<<128, 256, 0, stream>>>(cntG);
    k_rscatter<2><<<dim3(NSEG, 128), 256, 0, stream>>>(keyA, nullptr, nullptr, vs, idxv, cntG, 54);

    k_gather4<<<512, 768, 0, stream>>>(idxv, qkvI, g4);

    k_attn_qk<<<dim3(NCHUNK, 16), 256, 0, stream>>>(g4, partS, partN);
    k_attn_softmax<<<16, 256, 0, stream>>>(partS, partN, temp, attnT);
    k_attn_av<<<dim3(36, 16), 256, 0, stream>>>(attnT, vs, O1, O2);

    k_prod_scatter<<<dim3(144, 128), 256, 0, stream>>>(O1, O2, idxv, pu);
    k_gemm_proj<<<dim3(144, 2, 2), 256, 0, stream>>>(wp, pu, op);
    k_final<<<18432, 256, 0, stream>>>(op, idx_h, idx_w, out);
}

// Round 16
// 1092.508 us; speedup vs baseline: 1.1235x; 1.0671x over previous
//
#include <hip/hip_runtime.h>
#include <stdint.h>
#include <stddef.h>

constexpr int IMH = 192;
constexpr int IMW = 192;
constexpr int HW  = 36864;   // 192*192
constexpr int BB  = 2;
constexpr int CC  = 64;
constexpr int CHF = 32;      // half channels (sorted part)
constexpr int C5  = 320;     // 5*CC
constexpr int NQ  = 9216;    // HW/4
constexpr int CROWS = 64;    // fuse-pipeline chunk rows
constexpr int CHWN  = CROWS * IMW;  // 12288 cols per chunk
constexpr int NCHUNK = 32;   // attn_qk n-chunks per z
constexpr int CHN = HW / 4 / NCHUNK;  // 288 n per chunk
constexpr int NSEG = 12;     // radix segments per row (cntG fits the free hole exactly)
constexpr int SEGN = HW / NSEG;      // 3072 elements per segment (= 12 * 256)
constexpr int NBIN = 2048;   // 11-bit radix

typedef float fx2 __attribute__((ext_vector_type(2)));
typedef float fx4 __attribute__((ext_vector_type(4)));
typedef _Float16 f16;
typedef _Float16 f16x8 __attribute__((ext_vector_type(8)));
typedef float f32x4 __attribute__((ext_vector_type(4)));

// ---------- float <-> monotone uint32 (order-preserving, invertible) ----------
static __device__ __forceinline__ uint32_t f2s(float f) {
    uint32_t u = __float_as_uint(f);
    return (u & 0x80000000u) ? ~u : (u | 0x80000000u);
}
static __device__ __forceinline__ float s2f(uint32_t s) {
    uint32_t u = (s & 0x80000000u) ? (s & 0x7FFFFFFFu) : ~s;
    return __uint_as_float(u);
}

// ---------- multi-column bitonic: 256 slots x 16 lanes-wide in LDS, 256 threads ----------
static __device__ __forceinline__ void bitonic256x16(uint64_t (*keys)[17], int tid) {
    int wl = tid & 15;
    int p0 = tid >> 4;
    for (unsigned k = 2; k <= 256; k <<= 1) {
        for (unsigned j = k >> 1; j; j >>= 1) {
            __syncthreads();
            #pragma unroll
            for (int it = 0; it < 8; ++it) {
                unsigned pp = (unsigned)(p0 + it * 16);
                unsigned i = ((pp & ~(j - 1)) << 1) | (pp & (j - 1));
                unsigned q = i | j;
                bool up = ((i & k) == 0);
                uint64_t a = keys[i][wl], b = keys[q][wl];
                if ((a > b) == up) { keys[i][wl] = b; keys[q][wl] = a; }
            }
        }
    }
    __syncthreads();
}

// ---------- K1: stable sort along H, tiled: 16 adjacent w-columns per block ----------
__global__ __launch_bounds__(256) void k_sort_h(const float* __restrict__ x, float* __restrict__ A,
                                                int* __restrict__ idx_h) {
    __shared__ uint64_t keys[256][17];
    int tid = threadIdx.x;
    int blk = blockIdx.x;                 // b*CHF*12 + c*12 + wt
    int wt = blk % 12;
    int c  = (blk / 12) % CHF;
    int b  = blk / (12 * CHF);
    int w0 = wt * 16;
    const float* base = x + ((size_t)(b * CC) + c) * HW + w0;
    #pragma unroll
    for (int l = 0; l < 12; ++l) {
        int idx = l * 256 + tid;          // 0..3071
        int h = idx >> 4, wl = idx & 15;
        keys[h][wl] = (((uint64_t)f2s(base[(size_t)h * IMW + wl])) << 32) | (uint32_t)h;
    }
    #pragma unroll
    for (int l = 0; l < 4; ++l) {         // pad slots 192..255
        int idx = l * 256 + tid;
        keys[192 + (idx >> 4)][idx & 15] = ~0ull;
    }
    bitonic256x16(keys, tid);
    float* ocol = A + ((size_t)(b * CC) + c) * HW + w0;
    int* icol = idx_h + ((size_t)(b * CHF) + c) * HW + w0;
    #pragma unroll
    for (int l = 0; l < 12; ++l) {
        int idx = l * 256 + tid;
        int h = idx >> 4, wl = idx & 15;
        uint64_t kk = keys[h][wl];
        ocol[(size_t)h * IMW + wl] = s2f((uint32_t)(kk >> 32));
        icol[(size_t)h * IMW + wl] = (int)(kk & 0xFFFFFFFFull);
    }
}

// ---------- K2: stable sort along W, tiled: 16 rows per block, in-place on A ----------
__global__ __launch_bounds__(256) void k_sort_w(float* __restrict__ A, int* __restrict__ idx_w) {
    __shared__ uint64_t keys[256][17];
    int tid = threadIdx.x;
    int blk = blockIdx.x;                 // b*CHF*12 + c*12 + ht
    int ht = blk % 12;
    int c  = (blk / 12) % CHF;
    int b  = blk / (12 * CHF);
    int h0 = ht * 16;
    float* base = A + ((size_t)(b * CC) + c) * HW + (size_t)h0 * IMW;
    #pragma unroll
    for (int l = 0; l < 12; ++l) {
        int idx = l * 256 + tid;          // 0..3071
        int hl = idx / 192, w = idx % 192;
        keys[w][hl] = (((uint64_t)f2s(base[(size_t)hl * IMW + w])) << 32) | (uint32_t)w;
    }
    #pragma unroll
    for (int l = 0; l < 4; ++l) {         // pad slots 192..255
        int idx = l * 256 + tid;
        keys[192 + (idx >> 4)][idx & 15] = ~0ull;
    }
    bitonic256x16(keys, tid);
    int* irow = idx_w + ((size_t)(b * CHF) + c) * HW + (size_t)h0 * IMW;
    #pragma unroll
    for (int l = 0; l < 12; ++l) {
        int idx = l * 256 + tid;
        int hl = idx / 192, w = idx % 192;
        uint64_t kk = keys[w][hl];
        base[(size_t)hl * IMW + w] = s2f((uint32_t)(kk >> 32));
        irow[(size_t)hl * IMW + w] = (int)(kk & 0xFFFFFFFFull);
    }
}

// ---------- K3: q = W_qkv(320x64) * A(64xHW) per batch ----------
__global__ __launch_bounds__(256) void k_gemm_q(const float* __restrict__ wq, const float* __restrict__ A,
                                                const float* __restrict__ x, float* __restrict__ q) {
    __shared__ float Wt[64][68];
    __shared__ float Xt[64][68];
    int tid = threadIdx.x;
    int n0 = blockIdx.x * 64, m0 = blockIdx.y * 64, b = blockIdx.z;
    for (int l = 0; l < 16; ++l) {
        int idx = l * 256 + tid;
        int cc = idx & 63, m = idx >> 6;
        Wt[cc][m] = wq[(size_t)(m0 + m) * 64 + cc];
    }
    for (int l = 0; l < 16; ++l) {
        int idx = l * 256 + tid;
        int n = idx & 63, cc = idx >> 6;
        const float* sp = (cc < CHF) ? A : x;
        Xt[cc][n] = sp[((size_t)(b * CC) + cc) * HW + n0 + n];
    }
    __syncthreads();
    int ty = tid >> 4, tx = tid & 15;
    float acc[4][4] = {};
    for (int cc = 0; cc < 64; ++cc) {
        float4 av = *(const float4*)&Wt[cc][ty * 4];
        float4 bv = *(const float4*)&Xt[cc][tx * 4];
        float aa[4] = {av.x, av.y, av.z, av.w};
        float bb[4] = {bv.x, bv.y, bv.z, bv.w};
        #pragma unroll
        for (int i = 0; i < 4; ++i)
            #pragma unroll
            for (int j = 0; j < 4; ++j)
                acc[i][j] = fmaf(aa[i], bb[j], acc[i][j]);
    }
    for (int i = 0; i < 4; ++i) {
        float4 o;
        o.x = acc[i][0]; o.y = acc[i][1]; o.z = acc[i][2]; o.w = acc[i][3];
        *(float4*)&q[((size_t)(b * C5) + m0 + ty * 4 + i) * HW + n0 + tx * 4] = o;
    }
}

// ---------- K4: depthwise conv KSxKS (zero pad) for a 64-row chunk starting at r0 ----------
template <int KS>
__global__ __launch_bounds__(256) void k_dwconv(const float* __restrict__ q, const float* __restrict__ wd,
                                                float* __restrict__ slice, int r0) {
    constexpr int PAD = KS / 2;
    constexpr int EXT = 32 + 2 * PAD;
    __shared__ float tile[EXT][EXT];
    int tid = threadIdx.x;
    int b = blockIdx.z, c = blockIdx.y;
    int t = blockIdx.x;                  // 12 tiles: 2 tile-rows x 6 tile-cols
    int ty0 = r0 + (t / 6) * 32, tx0 = (t % 6) * 32;
    const float* src = q + ((size_t)(b * C5) + c) * HW;
    for (int i = tid; i < EXT * EXT; i += 256) {
        int iy = i / EXT, ix = i % EXT;
        int gy = ty0 + iy - PAD, gx = tx0 + ix - PAD;
        float v = 0.f;
        if (gy >= 0 && gy < IMH && gx >= 0 && gx < IMW) v = src[gy * IMW + gx];
        tile[iy][ix] = v;
    }
    __syncthreads();
    float wreg[KS * KS];
    #pragma unroll
    for (int i = 0; i < KS * KS; ++i) wreg[i] = wd[(size_t)c * KS * KS + i];
    float* dst = slice + ((size_t)(b * C5) + c) * CHWN;
    #pragma unroll
    for (int k = 0; k < 4; ++k) {
        int pix = k * 256 + tid;
        int py = pix >> 5, px = pix & 31;
        float acc = 0.f;
        #pragma unroll
        for (int ky = 0; ky < KS; ++ky)
            #pragma unroll
            for (int kx = 0; kx < KS; ++kx)
                acc = fmaf(tile[py + ky][px + kx], wreg[ky * KS + kx], acc);
        dst[(ty0 - r0 + py) * IMW + tx0 + px] = acc;
    }
}

// ---------- K5: qkv(chunk) (+)= W_fuse[:, g*320:(g+1)*320] * slice(chunk) ----------
// v6: MFMA f16x2 + INTERLEAVED output layout for q1/k1/q2/k2 (quad per (c,j));
// v-plane contiguous in qkvV for the radix sort.
__global__ __launch_bounds__(256) void k_gemm_fuse(const float* __restrict__ wf,
                                                   const float* __restrict__ slice, const float* __restrict__ bias,
                                                   float* __restrict__ qkvI, float* __restrict__ qkvV,
                                                   int g, int r0) {
    __shared__ f16 Ah[64][40];
    __shared__ f16 Al[64][40];
    int tid = threadIdx.x;
    int n0 = blockIdx.x * 128, py = blockIdx.y, m0 = py * 64, b = blockIdx.z;
    int lane = tid & 63, wv = tid >> 6;
    int l15 = lane & 15, lg = lane >> 4;
    int nwave = n0 + wv * 32;                 // wave's 32-col n-strip
    int sm = tid >> 2, skr = (tid & 3) * 8;   // W staging: m=tid>>2, 8 consecutive k
    int gk = g * 320;
    f32x4 acc[4][2];
    #pragma unroll
    for (int i = 0; i < 4; ++i)
        #pragma unroll
        for (int j = 0; j < 2; ++j)
            acc[i][j] = (f32x4){0.f, 0.f, 0.f, 0.f};

    const float* xcol = slice + (size_t)(b * C5) * CHWN + nwave + l15;
    const float* wrow = wf + (size_t)(m0 + sm) * 960 + gk + skr;

    for (int k0 = 0; k0 < 320; k0 += 32) {
        if (k0) __syncthreads();
        // stage W tile: fp32 -> f16 hi/lo split in registers -> LDS
        {
            float4 w0 = *(const float4*)(wrow + k0);
            float4 w1 = *(const float4*)(wrow + k0 + 4);
            float wvv[8] = {w0.x, w0.y, w0.z, w0.w, w1.x, w1.y, w1.z, w1.w};
            f16x8 hv, lv;
            #pragma unroll
            for (int j = 0; j < 8; ++j) {
                f16 h = (f16)wvv[j];
                hv[j] = h;
                lv[j] = (f16)(wvv[j] - (float)h);
            }
            *(f16x8*)&Ah[sm][skr] = hv;
            *(f16x8*)&Al[sm][skr] = lv;
        }
        float xv[2][8];
        #pragma unroll
        for (int fn = 0; fn < 2; ++fn)
            #pragma unroll
            for (int j = 0; j < 8; ++j)
                xv[fn][j] = xcol[(size_t)(k0 + lg * 8 + j) * CHWN + fn * 16];
        __syncthreads();
        f16x8 bh[2], bl[2];
        #pragma unroll
        for (int fn = 0; fn < 2; ++fn)
            #pragma unroll
            for (int j = 0; j < 8; ++j) {
                float v = xv[fn][j];
                f16 h = (f16)v;
                bh[fn][j] = h;
                bl[fn][j] = (f16)(v - (float)h);
            }
        #pragma unroll
        for (int fm = 0; fm < 4; ++fm) {
            f16x8 ah = *(const f16x8*)&Ah[fm * 16 + l15][lg * 8];
            f16x8 al = *(const f16x8*)&Al[fm * 16 + l15][lg * 8];
            #pragma unroll
            for (int fn = 0; fn < 2; ++fn) {
                acc[fm][fn] = __builtin_amdgcn_mfma_f32_16x16x32_f16(ah, bh[fn], acc[fm][fn], 0, 0, 0);
                acc[fm][fn] = __builtin_amdgcn_mfma_f32_16x16x32_f16(ah, bl[fn], acc[fm][fn], 0, 0, 0);
                acc[fm][fn] = __builtin_amdgcn_mfma_f32_16x16x32_f16(al, bh[fn], acc[fm][fn], 0, 0, 0);
            }
        }
    }

    #pragma unroll
    for (int fm = 0; fm < 4; ++fm) {
        #pragma unroll
        for (int r = 0; r < 4; ++r) {
            int m = m0 + fm * 16 + lg * 4 + r;
            int cg = m & 63;
            size_t colb = (size_t)r0 * IMW + nwave + l15;
            if (py < 4) {
                float* bp = qkvI + ((size_t)(b * CC + cg) * HW) * 4 + py;
                if (g == 0) {
                    float bv = bias[m];
                    #pragma unroll
                    for (int fn = 0; fn < 2; ++fn)
                        bp[(colb + fn * 16) * 4] = acc[fm][fn][r] + bv;
                } else {
                    #pragma unroll
                    for (int fn = 0; fn < 2; ++fn)
                        bp[(colb + fn * 16) * 4] += acc[fm][fn][r];
                }
            } else {
                float* bp = qkvV + (size_t)(b * CC + cg) * HW;
                if (g == 0) {
                    float bv = bias[m];
                    #pragma unroll
                    for (int fn = 0; fn < 2; ++fn)
                        bp[colb + fn * 16] = acc[fm][fn][r] + bv;
                } else {
                    #pragma unroll
                    for (int fn = 0; fn < 2; ++fn)
                        bp[colb + fn * 16] += acc[fm][fn][r];
                }
            }
        }
    }
}

// ---------- K6b-1: per-(row,seg) 11-bit digit histogram ----------
// FIRST=1: read qkvV v-plane directly (key formed on the fly, shift==32).
template <int FIRST>
__global__ __launch_bounds__(256) void k_rcount(const uint64_t* __restrict__ in, const float* __restrict__ qkvv,
                                                uint32_t* __restrict__ cntG, int shift) {
    __shared__ uint32_t hist[NBIN];
    int t = threadIdx.x;
    int seg = blockIdx.x, row = blockIdx.y;
    #pragma unroll
    for (int k = 0; k < NBIN / 256; ++k) hist[k * 256 + t] = 0;
    __syncthreads();
    if (FIRST) {
        const float* srcf = qkvv + (size_t)row * HW + (size_t)seg * SEGN;
        #pragma unroll
        for (int i = 0; i < SEGN / 256; ++i) {
            unsigned d = f2s(srcf[i * 256 + t]) & (NBIN - 1);   // shift==32
            atomicAdd(&hist[d], 1u);
        }
    } else {
        const uint64_t* src = in + (size_t)row * HW + (size_t)seg * SEGN;
        #pragma unroll
        for (int i = 0; i < SEGN / 256; ++i) {
            unsigned d = (unsigned)(src[i * 256 + t] >> shift) & (NBIN - 1);
            atomicAdd(&hist[d], 1u);
        }
    }
    __syncthreads();
    uint32_t* dstc = cntG + ((size_t)row * NSEG + seg) * NBIN;
    #pragma unroll
    for (int k = 0; k < NBIN / 256; ++k) dstc[k * 256 + t] = hist[k * 256 + t];
}

// ---------- K6b-2: per-row two-level scan -> absolute dest base per (seg,digit) ----------
__global__ __launch_bounds__(256) void k_rscan(uint32_t* __restrict__ cntG) {
    __shared__ uint32_t tot[NBIN];
    __shared__ uint32_t gsum[256];
    __shared__ uint32_t gbase[256];
    int t = threadIdx.x;
    int row = blockIdx.x;
    uint32_t* base = cntG + (size_t)row * NSEG * NBIN;
    uint32_t loc = 0;
    #pragma unroll
    for (int k = 0; k < NBIN / 256; ++k) {
        int bn = t * (NBIN / 256) + k;
        uint32_t s = 0;
        for (int sg = 0; sg < NSEG; ++sg) s += base[sg * NBIN + bn];
        tot[bn] = s;
        loc += s;
    }
    gsum[t] = loc;
    __syncthreads();
    if (t == 0) {
        uint32_t acc = 0;
        for (int i = 0; i < 256; ++i) { uint32_t v = gsum[i]; gbase[i] = acc; acc += v; }
    }
    __syncthreads();
    uint32_t run = gbase[t];
    #pragma unroll
    for (int k = 0; k < NBIN / 256; ++k) {
        int bn = t * (NBIN / 256) + k;
        uint32_t tv = tot[bn];
        uint32_t r2 = run;
        for (int sg = 0; sg < NSEG; ++sg) {
            uint32_t cv = base[sg * NBIN + bn];
            base[sg * NBIN + bn] = r2;
            r2 += cv;
        }
        run += tv;
    }
}

// ---------- K6b-3: stable scatter (11-bit) v4: preloaded keys + ballot rank + wave-ordered LDS atomics ----------
// MODE 0: key->key. MODE 1: qkvV->key. MODE 2: key->vs+idxv (unpack fused).
template <int MODE>
__global__ __launch_bounds__(256) void k_rscatter(const uint64_t* __restrict__ in, const float* __restrict__ qkvv,
                                                  uint64_t* __restrict__ out, float* __restrict__ vso,
                                                  int* __restrict__ idxo, const uint32_t* __restrict__ cntG,
                                                  int shift) {
    __shared__ uint32_t runbase[NBIN];
    int t = threadIdx.x;
    int w = t >> 6, lane = t & 63;
    int seg = blockIdx.x, row = blockIdx.y;
    const uint32_t* cbase = cntG + ((size_t)row * NSEG + seg) * NBIN;
    uint64_t kvp[SEGN / 256];
    if (MODE == 1) {
        const float* srcf = qkvv + (size_t)row * HW + (size_t)seg * SEGN;
        #pragma unroll
        for (int i = 0; i < SEGN / 256; ++i)
            kvp[i] = (((uint64_t)f2s(srcf[i * 256 + t])) << 32) | (uint32_t)(seg * SEGN + i * 256 + t);
    } else {
        const uint64_t* src = in + (size_t)row * HW + (size_t)seg * SEGN;
        #pragma unroll
        for (int i = 0; i < SEGN / 256; ++i)
            kvp[i] = src[i * 256 + t];
    }
    #pragma unroll
    for (int k = 0; k < NBIN / 256; ++k) runbase[k * 256 + t] = cbase[k * 256 + t];
    __syncthreads();
    #pragma unroll
    for (int i = 0; i < SEGN / 256; ++i) {
        uint64_t kv = kvp[i];
        unsigned d = (unsigned)(kv >> shift) & (NBIN - 1);
        uint64_t peers = ~0ull;
        #pragma unroll
        for (int bit = 0; bit < 11; ++bit) {
            uint64_t bm = __ballot((d >> bit) & 1u);
            peers &= ((d >> bit) & 1u) ? bm : ~bm;
        }
        unsigned lanerank = (unsigned)__popcll(peers & ((1ull << lane) - 1ull));
        unsigned wtotal = (unsigned)__popcll(peers);
        int leaderlane = __ffsll((unsigned long long)peers) - 1;
        unsigned base = 0;
        #pragma unroll
        for (int ww = 0; ww < 4; ++ww) {
            if (w == ww && lanerank == 0)
                base = atomicAdd(&runbase[d], wtotal);
            __syncthreads();
        }
        base = (unsigned)__shfl((int)base, leaderlane);
        unsigned pos = base + lanerank;
        if (MODE == 2) {
            vso[(size_t)row * HW + pos] = s2f((uint32_t)(kv >> 32));
            idxo[(size_t)row * HW + pos] = (int)(kv & 0xFFFFFFFFull);
        } else {
            out[(size_t)row * HW + pos] = kv;
        }
    }
}

// ---------- K6d: gather q1,k1,q2,k2 into sorted order (v7: quad-gather, 4-row L2 window) ----------
__global__ __launch_bounds__(768) void k_gather4(const int* __restrict__ idxv, const float* __restrict__ qkvI,
                                                 float* __restrict__ g4) {
    int i = blockIdx.x;
    int xcd = i & 7;
    int local = i >> 3;                          // 0..63
    int rsub = local & 3;
    int jseg = local >> 2;                       // 0..15
    size_t S4 = (size_t)BB * CC * HW;            // 4718592
    int tid = threadIdx.x;
    for (int ph = 0; ph < 4; ++ph) {
        int row = xcd * 16 + ph * 4 + rsub;
        const int* irow = idxv + (size_t)row * HW + jseg * 2304;
        const fx4* src = (const fx4*)(qkvI + (size_t)row * HW * 4);
        size_t dbase = (size_t)row * HW + jseg * 2304;
        float* d0 = g4 + dbase;
        float* d1 = d0 + S4;
        float* d2 = d0 + 2 * S4;
        float* d3 = d0 + 3 * S4;
        #pragma unroll
        for (int s = 0; s < 3; ++s) {
            int j = s * 768 + tid;
            int p = irow[j];
            fx4 a = src[p];
            __builtin_nontemporal_store(a.x, &d0[j]);
            __builtin_nontemporal_store(a.y, &d1[j]);
            __builtin_nontemporal_store(a.z, &d2[j]);
            __builtin_nontemporal_store(a.w, &d3[j]);
        }
        __syncthreads();                         // keep the XCD's blocks in the same phase
    }
}

// ---------- K7a: S partials + norm^2 partials, streaming from g4 ----------
__global__ __launch_bounds__(256) void k_attn_qk(const float* __restrict__ g4,
                                                 float* __restrict__ partS, float* __restrict__ partN) {
    __shared__ float Qs[16][68];
    __shared__ float Ks[16][68];
    __shared__ float nqs[4][64];
    __shared__ float nks[4][64];
    int tid = threadIdx.x;
    int ychunk = blockIdx.x;   // NCHUNK chunks of CHN
    int z = blockIdx.y;        // 16 = b(2) x h(4) x variant(2)
    int vi = z & 1, hh = (z >> 1) & 3, b = z >> 3;
    size_t S4 = (size_t)BB * CC * HW;
    const float* Q = g4 + (vi ? 2 * S4 : (size_t)0);
    const float* Kp = g4 + (vi ? 3 * S4 : S4);
    int ty = tid >> 4, tx = tid & 15;
    float acc[4][4] = {};
    float nq = 0.f, nk = 0.f;
    int d0 = tid & 63, kset = tid >> 6;
    int nbase0 = ychunk * CHN;
    for (int it = 0; it < CHN / 16; ++it) {
        int nb0 = nbase0 + it * 16;
        __syncthreads();
        #pragma unroll
        for (int l = 0; l < 4; ++l) {
            int idx = l * 256 + tid;
            int d = idx >> 4, kk = idx & 15;
            int n = nb0 + kk;
            int cch = hh * 16 + (d >> 2), f = d & 3;
            size_t off = ((size_t)(b * CC) + cch) * HW + (vi ? (size_t)(n * 4 + f) : (size_t)(f * NQ + n));
            Qs[kk][d] = Q[off];
            Ks[kk][d] = Kp[off];
        }
        __syncthreads();
        #pragma unroll
        for (int kk = 0; kk < 16; ++kk) {
            float4 av = *(const float4*)&Qs[kk][ty * 4];
            float4 bv = *(const float4*)&Ks[kk][tx * 4];
            float aa[4] = {av.x, av.y, av.z, av.w};
            float bb[4] = {bv.x, bv.y, bv.z, bv.w};
            #pragma unroll
            for (int i = 0; i < 4; ++i)
                #pragma unroll
                for (int j = 0; j < 4; ++j)
                    acc[i][j] = fmaf(aa[i], bb[j], acc[i][j]);
        }
        #pragma unroll
        for (int kk2 = 0; kk2 < 4; ++kk2) {
            float qv = Qs[kset * 4 + kk2][d0];
            float kv = Ks[kset * 4 + kk2][d0];
            nq = fmaf(qv, qv, nq);
            nk = fmaf(kv, kv, nk);
        }
    }
    size_t sb = ((size_t)z * NCHUNK + ychunk) * 4096;
    #pragma unroll
    for (int i = 0; i < 4; ++i)
        #pragma unroll
        for (int j = 0; j < 4; ++j)
            partS[sb + (size_t)(ty * 4 + i) * 64 + tx * 4 + j] = acc[i][j];
    nqs[kset][d0] = nq;
    nks[kset][d0] = nk;
    __syncthreads();
    if (tid < 64) {
        float sq = nqs[0][tid] + nqs[1][tid] + nqs[2][tid] + nqs[3][tid];
        float sk = nks[0][tid] + nks[1][tid] + nks[2][tid] + nks[3][tid];
        size_t nb2 = ((size_t)z * NCHUNK + ychunk) * 128;
        partN[nb2 + tid] = sq;
        partN[nb2 + 64 + tid] = sk;
    }
}

// ---------- K7a2: parallel reduce of partS/partN over NCHUNK ----------
// Round-14 counters: k_attn_softmax did this reduction with 16 blocks at 0.67%
// occupancy (60us, latency-bound). 65536 threads here, same FP order (ch-ascending).
__global__ __launch_bounds__(256) void k_attn_reduce(const float* __restrict__ partS,
                                                     const float* __restrict__ partN,
                                                     float* __restrict__ partSr, float* __restrict__ partNr) {
    int i = blockIdx.x * 256 + threadIdx.x;      // 65536 = 16 z * 4096
    int z = i >> 12, de = i & 4095;
    const float* p = partS + ((size_t)z * NCHUNK) * 4096 + de;
    float s = 0.f;
    #pragma unroll
    for (int ch = 0; ch < NCHUNK; ++ch) s += p[ch * 4096];
    partSr[i] = s;
    if (i < 16 * 128) {
        int z2 = i >> 7, t2 = i & 127;
        const float* pn = partN + ((size_t)z2 * NCHUNK) * 128 + t2;
        float s2 = 0.f;
        #pragma unroll
        for (int ch = 0; ch < NCHUNK; ++ch) s2 += pn[ch * 128];
        partNr[i] = s2;
    }
}

// ---------- K7b: normalize, exp, denom = rowsum+1 ; write attn^T (reads reduced arrays) ----------
__global__ __launch_bounds__(256) void k_attn_softmax(const float* __restrict__ partSr,
                                                      const float* __restrict__ partNr,
                                                      const float* __restrict__ temp, float* __restrict__ attnT) {
    __shared__ float nqv[64], nkv[64];
    __shared__ float pbuf[64][65];
    __shared__ float rred[64][4];
    __shared__ float rsum[64];
    int tid = threadIdx.x;
    int z = blockIdx.x;
    int hh = (z >> 1) & 3;
    if (tid < 128) {
        float s = partNr[(size_t)z * 128 + tid];
        float nv = fmaxf(sqrtf(s), 1e-12f);
        if (tid < 64) nqv[tid] = nv; else nkv[tid - 64] = nv;
    }
    __syncthreads();
    float tf = temp[hh];
    int d = tid >> 2, qq = tid & 3;
    float psum = 0.f;
    for (int e = qq * 16; e < qq * 16 + 16; ++e) {
        float s = partSr[(size_t)z * 4096 + (size_t)d * 64 + e];
        float p = expf(tf * s / (nqv[d] * nkv[e]));
        pbuf[d][e] = p;
        psum += p;
    }
    rred[d][qq] = psum;
    __syncthreads();
    if (tid < 64) rsum[tid] = rred[tid][0] + rred[tid][1] + rred[tid][2] + rred[tid][3] + 1.0f;
    __syncthreads();
    for (int e = qq * 16; e < qq * 16 + 16; ++e)
        attnT[(size_t)z * 4096 + (size_t)e * 64 + d] = pbuf[d][e] / rsum[d];
}

// ---------- K7c: O = attn * V, written back to (c, sorted-position) layout ----------
__global__ __launch_bounds__(256) void k_attn_av(const float* __restrict__ attnT, const float* __restrict__ vs,
                                                 float* __restrict__ O1, float* __restrict__ O2) {
    __shared__ float at_s[4096];
    int tid = threadIdx.x;
    int z = blockIdx.y;
    int vi = z & 1, hh = (z >> 1) & 3, b = z >> 3;
    for (int l = 0; l < 16; ++l) at_s[l * 256 + tid] = attnT[(size_t)z * 4096 + l * 256 + tid];
    __syncthreads();
    int n = blockIdx.x * 256 + tid;
    float acc[64];
    #pragma unroll
    for (int d = 0; d < 64; ++d) acc[d] = 0.f;
    for (int e = 0; e < 64; ++e) {
        int cch = hh * 16 + (e >> 2), f = e & 3;
        size_t p = vi ? (size_t)(n * 4 + f) : (size_t)(f * NQ + n);
        float vv = vs[((size_t)(b * CC) + cch) * HW + p];
        const float* ar = &at_s[e * 64];
        #pragma unroll
        for (int d4 = 0; d4 < 16; ++d4) {
            float4 a4 = *(const float4*)&ar[d4 * 4];
            acc[d4 * 4 + 0] = fmaf(a4.x, vv, acc[d4 * 4 + 0]);
            acc[d4 * 4 + 1] = fmaf(a4.y, vv, acc[d4 * 4 + 1]);
            acc[d4 * 4 + 2] = fmaf(a4.z, vv, acc[d4 * 4 + 2]);
            acc[d4 * 4 + 3] = fmaf(a4.w, vv, acc[d4 * 4 + 3]);
        }
    }
    float* Ob = vi ? O2 : O1;
    #pragma unroll
    for (int d = 0; d < 64; ++d) {
        int cch = hh * 16 + (d >> 2), f = d & 3;
        size_t p = vi ? (size_t)(n * 4 + f) : (size_t)(f * NQ + n);
        Ob[((size_t)(b * CC) + cch) * HW + p] = acc[d];
    }
}

// ---------- K8: product in sorted domain, scatter to original positions via idxv ----------
__global__ void k_prod_scatter(const float* __restrict__ O1, const float* __restrict__ O2,
                               const int* __restrict__ idxv, float* __restrict__ pu) {
    int j = blockIdx.x * 256 + threadIdx.x;
    int row = blockIdx.y;
    size_t o = (size_t)row * HW + j;
    int p = idxv[o];
    pu[(size_t)row * HW + p] = O1[o] * O2[o];
}

// ---------- K9: proj GEMM 64x64 ----------
__global__ __launch_bounds__(256) void k_gemm_proj(const float* __restrict__ wp, const float* __restrict__ pu,
                                                   float* __restrict__ op) {
    __shared__ float wt[2048];  // wt[c*32+mm] = wp[(mh*32+mm)*64+c]
    int tid = threadIdx.x;
    int mh = blockIdx.y, b = blockIdx.z;
    for (int l = 0; l < 8; ++l) {
        int i = l * 256 + tid;
        int mm = i >> 6, c = i & 63;
        wt[c * 32 + mm] = wp[(size_t)(mh * 32 + mm) * 64 + c];
    }
    __syncthreads();
    int n = blockIdx.x * 256 + tid;
    float acc[32];
    #pragma unroll
    for (int m = 0; m < 32; ++m) acc[m] = 0.f;
    const float* src = pu + (size_t)(b * CC) * HW + n;
    for (int c = 0; c < 64; ++c) {
        float xv = src[(size_t)c * HW];
        const float* wr = &wt[c * 32];
        #pragma unroll
        for (int m4 = 0; m4 < 8; ++m4) {
            float4 w4 = *(const float4*)&wr[m4 * 4];
            acc[m4 * 4 + 0] = fmaf(w4.x, xv, acc[m4 * 4 + 0]);
            acc[m4 * 4 + 1] = fmaf(w4.y, xv, acc[m4 * 4 + 1]);
            acc[m4 * 4 + 2] = fmaf(w4.z, xv, acc[m4 * 4 + 2]);
            acc[m4 * 4 + 3] = fmaf(w4.w, xv, acc[m4 * 4 + 3]);
        }
    }
    float* dst = op + ((size_t)(b * CC) + mh * 32) * HW + n;
    for (int m = 0; m < 32; ++m) dst[(size_t)m * HW] = acc[m];
}

// ---------- K10: spatial unsort scatter for c<32, copy c>=32 ----------
__global__ void k_final(const float* __restrict__ op, const int* __restrict__ idx_h,
                        const int* __restrict__ idx_w, float* __restrict__ out) {
    int i = blockIdx.x * 256 + threadIdx.x;
    int p = i % HW;
    int c = (i / HW) % CC;
    int b = i / (HW * CC);
    float v = op[i];
    if (c < CHF) {
        int h = p / IMW, w = p % IMW;
        size_t ib = ((size_t)(b * CHF) + c) * HW;
        int W0 = idx_w[ib + h * IMW + w];
        int H0 = idx_h[ib + h * IMW + W0];
        out[((size_t)(b * CC) + c) * HW + H0 * IMW + W0] = v;
    } else {
        out[i] = v;
    }
}

extern "C" void kernel_launch(void* const* d_in, const int* in_sizes, int n_in,
                              void* d_out, int out_size, void* d_ws, size_t ws_size,
                              hipStream_t stream) {
    (void)in_sizes; (void)n_in; (void)out_size; (void)ws_size;
    const float* x    = (const float*)d_in[0];
    const float* temp = (const float*)d_in[1];
    const float* wq   = (const float*)d_in[2];
    const float* wd3  = (const float*)d_in[3];
    const float* wd5  = (const float*)d_in[4];
    const float* wd7  = (const float*)d_in[5];
    const float* wf   = (const float*)d_in[6];
    const float* bf   = (const float*)d_in[7];
    const float* wp   = (const float*)d_in[8];
    float* out = (float*)d_out;
    float* ws = (float*)d_ws;

    // ---- workspace arena (~228 MiB) — aliasing as verified in Rounds 7/9 ----
    int*      idx_h = (int*)(ws + 0);
    int*      idx_w = (int*)(ws + 2359296);
    float*    A     = ws + 4718592;
    float*    slice = ws + 4718592;                    // over dead A
    float*    q     = ws + 12582912;
    float*    qkvI  = ws + 36175872;                   // ..55050240 — live until gather4 done
    float*    qkvV  = ws + 55050240;                   // ..59768832 — dead after radix pass 0
    int*      idxv  = (int*)(ws + 4718592);            // over dead slice: 4718592..9437184
    uint32_t* cntG  = (uint32_t*)(ws + 9437184);       // 128*12*2048 u32 = 3145728 — exact fit 9437184..12582912
    uint64_t* keyA  = (uint64_t*)(ws + 12582912);      // over dead q: ..22020096
    uint64_t* keyB  = (uint64_t*)(ws + 22020096);      // ..31457280
    float*    vs    = ws + 31457280;                   // ..36175872
    float*    g4    = ws + 12582912;                   // over dead keyA+keyB (after radix)
    float*    O1    = ws + 36175872;                   // over dead qkvI (after gather4)
    float*    O2    = ws + 40894464;
    float*    pu    = ws + 45613056;
    float*    op    = ws + 50331648;                   // written by k_gemm_proj
    float*    partS = ws + 55050240;                   // over dead qkvV (written by attn_qk)
    float*    partN = ws + 57147392;
    float*    attnT = ws + 57212928;                   // ..57278464
    float*    partSr= ws + 57278464;                   // 65536 -> ..57344000
    float*    partNr= ws + 57344000;                   // 2048  -> ..57346048 (< 59768832, over dead qkvV)

    k_sort_h<<<768, 256, 0, stream>>>(x, A, idx_h);
    k_sort_w<<<768, 256, 0, stream>>>(A, idx_w);
    k_gemm_q<<<dim3(576, 5, 2), 256, 0, stream>>>(wq, A, x, q);

    for (int g = 0; g < 3; ++g) {
        for (int chunk = 0; chunk < 3; ++chunk) {
            int r0 = chunk * CROWS;
            if (g == 0)      k_dwconv<3><<<dim3(12, 320, 2), 256, 0, stream>>>(q, wd3, slice, r0);
            else if (g == 1) k_dwconv<5><<<dim3(12, 320, 2), 256, 0, stream>>>(q, wd5, slice, r0);
            else             k_dwconv<7><<<dim3(12, 320, 2), 256, 0, stream>>>(q, wd7, slice, r0);
            k_gemm_fuse<<<dim3(96, 5, 2), 256, 0, stream>>>(wf, slice, bf, qkvI, qkvV, g, r0);
        }
    }

    // 3 stable LSD passes of 11 bits over the value (bits 32..63).
    k_rcount<1><<<dim3(NSEG, 128), 256, 0, stream>>>(nullptr, qkvV, cntG, 32);
    k_rscan<<<128, 256, 0, stream>>>(cntG);
    k_rscatter<1><<<dim3(NSEG, 128), 256, 0, stream>>>(nullptr, qkvV, keyB, nullptr, nullptr, cntG, 32);
    k_rcount<0><<<dim3(NSEG, 128), 256, 0, stream>>>(keyB, nullptr, cntG, 43);
    k_rscan<<<128, 256, 0, stream>>>(cntG);
    k_rscatter<0><<<dim3(NSEG, 128), 256, 0, stream>>>(keyB, nullptr, keyA, nullptr, nullptr, cntG, 43);
    k_rcount<0><<<dim3(NSEG, 128), 256, 0, stream>>>(keyA, nullptr, cntG, 54);
    k_rscan<<<128, 256, 0, stream>>>(cntG);
    k_rscatter<2><<<dim3(NSEG, 128), 256, 0, stream>>>(keyA, nullptr, nullptr, vs, idxv, cntG, 54);

    k_gather4<<<512, 768, 0, stream>>>(idxv, qkvI, g4);

    k_attn_qk<<<dim3(NCHUNK, 16), 256, 0, stream>>>(g4, partS, partN);
    k_attn_reduce<<<256, 256, 0, stream>>>(partS, partN, partSr, partNr);
    k_attn_softmax<<<16, 256, 0, stream>>>(partSr, partNr, temp, attnT);
    k_attn_av<<<dim3(36, 16), 256, 0, stream>>>(attnT, vs, O1, O2);

    k_prod_scatter<<<dim3(144, 128), 256, 0, stream>>>(O1, O2, idxv, pu);
    k_gemm_proj<<<dim3(144, 2, 2), 256, 0, stream>>>(wp, pu, op);
    k_final<<<18432, 256, 0, stream>>>(op, idx_h, idx_w, out);
}